// Round 1
// baseline (23661.777 us; speedup 1.0000x reference)
//
#include <hip/hip_runtime.h>
#include <math.h>

#define BH   8
#define SEQT 4096
#define DD   512
#define DI_  512
#define CS_  256
#define NUP  15

// ---------------- workspace layout (float offsets) ----------------
#define SZ_W    (3ull*BH*DI_*DD)        /* 6,291,456  */
#define SZ_W1   ((size_t)BH*DI_*DD)     /* 2,097,152  */
#define SZ_ACT  ((size_t)BH*DI_*CS_)    /* 1,048,576  */
#define OFF_WM  0ull
#define OFF_WC  (OFF_WM + SZ_W)
#define OFF_DM  (OFF_WC + SZ_W)
#define OFF_X   (OFF_DM + SZ_W)
#define OFF_A   (OFF_X  + SZ_W)
#define OFF_SQ  (OFF_A  + SZ_W)
#define OFF_GBA (OFF_SQ  + SZ_ACT)
#define OFF_HBM (OFF_GBA + SZ_ACT)
#define OFF_HID (OFF_HBM + SZ_ACT)
#define OFF_DGB (OFF_HID + SZ_ACT)
#define OFF_DHB (OFF_DGB + SZ_ACT)
#define OFF_Y   OFF_SQ                  /* overlay: NS Y reuses dead activation bufs */
#define OFF_FRO (OFF_DHB + SZ_ACT)      /* 15*24 */
#define OFF_MI  (OFF_FRO + 360)         /* 120 */
#define OFF_MLI (OFF_MI  + 120)         /* 120 */
#define OFF_WN  (OFF_MLI + 120)         /* 12288 */

__device__ __forceinline__ float sigm(float x){ return 1.0f/(1.0f+expf(-x)); }

#define FMA44(ACC,AV,BV) do{ \
  ACC[0][0]+=AV.x*BV.x; ACC[0][1]+=AV.x*BV.y; ACC[0][2]+=AV.x*BV.z; ACC[0][3]+=AV.x*BV.w; \
  ACC[1][0]+=AV.y*BV.x; ACC[1][1]+=AV.y*BV.y; ACC[1][2]+=AV.y*BV.z; ACC[1][3]+=AV.y*BV.w; \
  ACC[2][0]+=AV.z*BV.x; ACC[2][1]+=AV.z*BV.y; ACC[2][2]+=AV.z*BV.z; ACC[2][3]+=AV.z*BV.w; \
  ACC[3][0]+=AV.w*BV.x; ACC[3][1]+=AV.w*BV.y; ACC[3][2]+=AV.w*BV.z; ACC[3][3]+=AV.w*BV.w; \
}while(0)

// C[m][n] = sum_k A[m][k]*B[k][n]  (A row-major lda, B row-major ldb); optional per-k scale on B rows.
__device__ __forceinline__ void gemm_nn_tile(
    const float* __restrict__ A, int lda,
    const float* __restrict__ B, int ldb,
    const float* __restrict__ lsc,
    int K, int m0, int n0, float acc[4][4],
    float (&As)[16][68], float (&Bs)[16][68])
{
  const int tid = threadIdx.x;
  const int ar = tid >> 2, ac = (tid & 3) << 2;
  const int br = tid >> 4, bc = (tid & 15) << 2;
  const int my = tid & 15, nx = tid >> 4;
  for (int k0 = 0; k0 < K; k0 += 16) {
    float4 av = *(const float4*)&A[(size_t)(m0 + ar) * lda + k0 + ac];
    float4 bv = *(const float4*)&B[(size_t)(k0 + br) * ldb + n0 + bc];
    if (lsc) { float s = lsc[k0 + br]; bv.x*=s; bv.y*=s; bv.z*=s; bv.w*=s; }
    __syncthreads();
    As[ac+0][ar]=av.x; As[ac+1][ar]=av.y; As[ac+2][ar]=av.z; As[ac+3][ar]=av.w;
    *(float4*)&Bs[br][bc] = bv;
    __syncthreads();
    #pragma unroll
    for (int kk = 0; kk < 16; ++kk) {
      float4 a = *(const float4*)&As[kk][my*4];
      float4 b = *(const float4*)&Bs[kk][nx*4];
      FMA44(acc,a,b);
    }
  }
}

// -------- fwd: P0 = w0c@S^T, P2 = w2c@S^T ; S = q-chunk or k-chunk (NT, dual A) --------
__global__ __launch_bounds__(256) void fwd_kernel(
    const float* __restrict__ w0c, const float* __restrict__ w2c,
    const float* __restrict__ q, const float* __restrict__ kin,
    float* __restrict__ sq, float* __restrict__ gba,
    float* __restrict__ hbmp, float* __restrict__ hid,
    int c, int nsrc)
{
  __shared__ float As0[16][68], As1[16][68], Bs[16][68];
  const int b = blockIdx.x;
  const int nt = b & 3, mt = (b >> 2) & 7;
  const int src = (b >> 5) % nsrc;
  const int bh = b / (32 * nsrc);
  const int m0 = mt * 64, n0 = nt * 64;
  const float* A0 = w0c + (size_t)bh * DI_ * DD;
  const float* A1 = w2c + (size_t)bh * DI_ * DD;
  const float* S  = (src == 0 ? q : kin) + ((size_t)bh * SEQT + (size_t)c * CS_) * DD;
  float acc0[4][4] = {}, acc1[4][4] = {};
  const int tid = threadIdx.x;
  const int r = tid >> 2, c4 = (tid & 3) << 2;
  const int my = tid & 15, nx = tid >> 4;
  for (int k0 = 0; k0 < DD; k0 += 16) {
    float4 a0 = *(const float4*)&A0[(size_t)(m0 + r) * DD + k0 + c4];
    float4 a1 = *(const float4*)&A1[(size_t)(m0 + r) * DD + k0 + c4];
    float4 bv = *(const float4*)&S [(size_t)(n0 + r) * DD + k0 + c4];
    __syncthreads();
    As0[c4+0][r]=a0.x; As0[c4+1][r]=a0.y; As0[c4+2][r]=a0.z; As0[c4+3][r]=a0.w;
    As1[c4+0][r]=a1.x; As1[c4+1][r]=a1.y; As1[c4+2][r]=a1.z; As1[c4+3][r]=a1.w;
    Bs [c4+0][r]=bv.x; Bs [c4+1][r]=bv.y; Bs [c4+2][r]=bv.z; Bs [c4+3][r]=bv.w;
    __syncthreads();
    #pragma unroll
    for (int kk = 0; kk < 16; ++kk) {
      float4 a  = *(const float4*)&As0[kk][my*4];
      float4 a2 = *(const float4*)&As1[kk][my*4];
      float4 bb = *(const float4*)&Bs [kk][nx*4];
      FMA44(acc0,a,bb);
      FMA44(acc1,a2,bb);
    }
  }
  #pragma unroll
  for (int um = 0; um < 4; ++um) {
    int j = m0 + my*4 + um;
    size_t base = ((size_t)bh * DI_ + j) * CS_ + n0 + nx*4;
    if (src == 0) {
      float4 o;
      o.x = acc0[um][0]*sigm(acc0[um][0])*acc1[um][0];
      o.y = acc0[um][1]*sigm(acc0[um][1])*acc1[um][1];
      o.z = acc0[um][2]*sigm(acc0[um][2])*acc1[um][2];
      o.w = acc0[um][3]*sigm(acc0[um][3])*acc1[um][3];
      *(float4*)&sq[base] = o;
    } else {
      float4 g = make_float4(acc0[um][0],acc0[um][1],acc0[um][2],acc0[um][3]);
      float4 h = make_float4(acc1[um][0],acc1[um][1],acc1[um][2],acc1[um][3]);
      float4 hd;
      hd.x = g.x*sigm(g.x)*h.x; hd.y = g.y*sigm(g.y)*h.y;
      hd.z = g.z*sigm(g.z)*h.z; hd.w = g.w*sigm(g.w)*h.w;
      *(float4*)&gba[base]  = g;
      *(float4*)&hbmp[base] = h;
      *(float4*)&hid[base]  = hd;
    }
  }
}

// -------- out: C[d][t] = w1c @ sq ; write out[bh][c*CS+t][d] --------
__global__ __launch_bounds__(256) void out_kernel(
    const float* __restrict__ w1c, const float* __restrict__ sq,
    float* __restrict__ out, int c)
{
  __shared__ float As[16][68], Bs[16][68];
  const int b = blockIdx.x;
  const int nt = b & 3, mt = (b >> 2) & 7, bh = b >> 5;
  const int m0 = mt * 64, n0 = nt * 64;
  float acc[4][4] = {};
  gemm_nn_tile(w1c + (size_t)bh*DD*DI_, DI_, sq + (size_t)bh*DI_*CS_, CS_,
               nullptr, DI_, m0, n0, acc, As, Bs);
  const int my = threadIdx.x & 15, nx = threadIdx.x >> 4;
  #pragma unroll
  for (int un = 0; un < 4; ++un) {
    int t = n0 + nx*4 + un;
    float4 o = make_float4(acc[0][un],acc[1][un],acc[2][un],acc[3][un]);
    *(float4*)&out[((size_t)bh*SEQT + (size_t)c*CS_ + t)*DD + m0 + my*4] = o;
  }
}

// -------- dh: E[t][j] = v_chunk @ w1c ; epilogue -> dgba, dhbm --------
__global__ __launch_bounds__(256) void dh_kernel(
    const float* __restrict__ vin, const float* __restrict__ w1c,
    const float* __restrict__ gba, const float* __restrict__ hbmp,
    float* __restrict__ dgb, float* __restrict__ dhb, int c)
{
  __shared__ float As[16][68], Bs[16][68];
  const int b = blockIdx.x;
  const int nt = b & 7, mt = (b >> 3) & 3, bh = b >> 5;
  const int m0 = mt * 64, n0 = nt * 64;
  float acc[4][4] = {};
  gemm_nn_tile(vin + ((size_t)bh*SEQT + (size_t)c*CS_)*DD, DD,
               w1c + (size_t)bh*DD*DI_, DI_, nullptr, DD, m0, n0, acc, As, Bs);
  const int my = threadIdx.x & 15, nx = threadIdx.x >> 4;
  #pragma unroll
  for (int un = 0; un < 4; ++un) {
    int j = n0 + nx*4 + un;
    size_t idx = ((size_t)bh*DI_ + j)*CS_ + m0 + my*4;
    float4 g4 = *(const float4*)&gba[idx];
    float4 h4 = *(const float4*)&hbmp[idx];
    float ge[4] = {g4.x,g4.y,g4.z,g4.w};
    float hb[4] = {h4.x,h4.y,h4.z,h4.w};
    float dg[4], dh[4];
    #pragma unroll
    for (int u = 0; u < 4; ++u) {
      float e = acc[u][un];
      float s = sigm(ge[u]);
      dh[u] = e * ge[u] * s;                      // dhidden * silu(gba)
      float dgate = e * hb[u];
      dg[u] = dgate * s * (1.f + ge[u]*(1.f - s)); // silu_bp
    }
    *(float4*)&dgb[idx] = make_float4(dg[0],dg[1],dg[2],dg[3]);
    *(float4*)&dhb[idx] = make_float4(dh[0],dh[1],dh[2],dh[3]);
  }
}

// -------- dw: C[j][d] = A[j][t]*(B[t][d]*lr[t]) ; + momentum ; fro accumulate --------
// w=0: dgba*k*lr0 ; w=1: hidden*v*lr1 (dw1 TRANSPOSED) ; w=2: dhbm*k*lr2
__global__ __launch_bounds__(256) void dw_kernel(
    const float* __restrict__ dgb, const float* __restrict__ dhb,
    const float* __restrict__ hid, const float* __restrict__ kin,
    const float* __restrict__ vin,
    const float* __restrict__ lr0, const float* __restrict__ lr1,
    const float* __restrict__ lr2,
    float* __restrict__ dm, float* __restrict__ X,
    const float* __restrict__ mi, float* __restrict__ fro, int c)
{
  __shared__ float As[16][68], Bs[16][68];
  __shared__ float red[4];
  const int b = blockIdx.x;
  const int nt = b & 7, mt = (b >> 3) & 7, bh = (b >> 6) & 7, w = b >> 9;
  const int m0 = mt * 64, n0 = nt * 64;
  const float* Aop = (w==0 ? dgb : (w==1 ? hid : dhb)) + (size_t)bh*DI_*CS_;
  const float* Bop = (w==1 ? vin : kin) + ((size_t)bh*SEQT + (size_t)c*CS_)*DD;
  const float* l   = (w==0 ? lr0 : (w==1 ? lr1 : lr2)) + (size_t)bh*SEQT + (size_t)c*CS_;
  float acc[4][4] = {};
  gemm_nn_tile(Aop, CS_, Bop, DD, l, CS_, m0, n0, acc, As, Bs);
  const int my = threadIdx.x & 15, nx = threadIdx.x >> 4;
  const float m_i = mi[bh*NUP + c];
  const int mat = bh*3 + w;
  const size_t base = (size_t)mat * DI_ * DD;
  float fs = 0.f;
  #pragma unroll
  for (int um = 0; um < 4; ++um) {
    size_t idx = base + (size_t)(m0 + my*4 + um)*DD + n0 + nx*4;
    float4 dmv = *(const float4*)&dm[idx];
    float4 dv;
    dv.x = acc[um][0] + dmv.x*m_i; dv.y = acc[um][1] + dmv.y*m_i;
    dv.z = acc[um][2] + dmv.z*m_i; dv.w = acc[um][3] + dmv.w*m_i;
    *(float4*)&dm[idx] = dv;
    *(float4*)&X[idx]  = dv;
    fs += dv.x*dv.x + dv.y*dv.y + dv.z*dv.z + dv.w*dv.w;
  }
  #pragma unroll
  for (int off = 32; off > 0; off >>= 1) fs += __shfl_down(fs, off, 64);
  const int wid = threadIdx.x >> 6;
  if ((threadIdx.x & 63) == 0) red[wid] = fs;
  __syncthreads();
  if (threadIdx.x == 0) atomicAdd(&fro[mat], red[0]+red[1]+red[2]+red[3]);
}

// -------- X *= 1/(||X||_F + 1e-7) --------
__global__ __launch_bounds__(256) void ns_scale_kernel(float* __restrict__ X,
                                                       const float* __restrict__ fro)
{
  int gid = blockIdx.x*256 + threadIdx.x;      // 6144*256 = 24 * 65536 float4
  int mat = gid >> 16;
  float inv = 1.0f/(sqrtf(fro[mat]) + 1e-7f);
  float4* p = ((float4*)X) + gid;
  float4 v = *p; v.x*=inv; v.y*=inv; v.z*=inv; v.w*=inv; *p = v;
}

// -------- NS: A = X @ X^T (NT, batch 24) --------
__global__ __launch_bounds__(256) void nsA_kernel(const float* __restrict__ X,
                                                  float* __restrict__ Ab)
{
  __shared__ float As[16][68], Bs[16][68];
  const int b = blockIdx.x;
  const int nt = b & 7, mt = (b >> 3) & 7, mat = b >> 6;
  const int m0 = mt*64, n0 = nt*64;
  const float* Xm = X + (size_t)mat * DI_ * DD;
  float acc[4][4] = {};
  const int tid = threadIdx.x;
  const int r = tid >> 2, c4 = (tid & 3) << 2;
  const int my = tid & 15, nx = tid >> 4;
  for (int k0 = 0; k0 < DD; k0 += 16) {
    float4 av = *(const float4*)&Xm[(size_t)(m0 + r)*DD + k0 + c4];
    float4 bv = *(const float4*)&Xm[(size_t)(n0 + r)*DD + k0 + c4];
    __syncthreads();
    As[c4+0][r]=av.x; As[c4+1][r]=av.y; As[c4+2][r]=av.z; As[c4+3][r]=av.w;
    Bs[c4+0][r]=bv.x; Bs[c4+1][r]=bv.y; Bs[c4+2][r]=bv.z; Bs[c4+3][r]=bv.w;
    __syncthreads();
    #pragma unroll
    for (int kk = 0; kk < 16; ++kk) {
      float4 a = *(const float4*)&As[kk][my*4];
      float4 bb = *(const float4*)&Bs[kk][nx*4];
      FMA44(acc,a,bb);
    }
  }
  #pragma unroll
  for (int um = 0; um < 4; ++um) {
    size_t idx = (size_t)mat*DI_*DD + (size_t)(m0 + my*4 + um)*DD + n0 + nx*4;
    *(float4*)&Ab[idx] = make_float4(acc[um][0],acc[um][1],acc[um][2],acc[um][3]);
  }
}

// -------- NS: Y = A @ X --------
__global__ __launch_bounds__(256) void nsY_kernel(const float* __restrict__ Ab,
                                                  const float* __restrict__ X,
                                                  float* __restrict__ Y)
{
  __shared__ float As[16][68], Bs[16][68];
  const int b = blockIdx.x;
  const int nt = b & 7, mt = (b >> 3) & 7, mat = b >> 6;
  const int m0 = mt*64, n0 = nt*64;
  float acc[4][4] = {};
  gemm_nn_tile(Ab + (size_t)mat*DI_*DD, DD, X + (size_t)mat*DI_*DD, DD,
               nullptr, DD, m0, n0, acc, As, Bs);
  const int my = threadIdx.x & 15, nx = threadIdx.x >> 4;
  #pragma unroll
  for (int um = 0; um < 4; ++um) {
    size_t idx = (size_t)mat*DI_*DD + (size_t)(m0 + my*4 + um)*DD + n0 + nx*4;
    *(float4*)&Y[idx] = make_float4(acc[um][0],acc[um][1],acc[um][2],acc[um][3]);
  }
}

// -------- NS: X = a*X + b*Y + c*(A@Y) --------
__global__ __launch_bounds__(256) void nsZ_kernel(const float* __restrict__ Ab,
                                                  const float* __restrict__ Y,
                                                  float* __restrict__ X,
                                                  float ca, float cb, float cg)
{
  __shared__ float As[16][68], Bs[16][68];
  const int b = blockIdx.x;
  const int nt = b & 7, mt = (b >> 3) & 7, mat = b >> 6;
  const int m0 = mt*64, n0 = nt*64;
  float acc[4][4] = {};
  gemm_nn_tile(Ab + (size_t)mat*DI_*DD, DD, Y + (size_t)mat*DI_*DD, DD,
               nullptr, DD, m0, n0, acc, As, Bs);
  const int my = threadIdx.x & 15, nx = threadIdx.x >> 4;
  #pragma unroll
  for (int um = 0; um < 4; ++um) {
    size_t idx = (size_t)mat*DI_*DD + (size_t)(m0 + my*4 + um)*DD + n0 + nx*4;
    float4 xv = *(const float4*)&X[idx];
    float4 yv = *(const float4*)&Y[idx];
    float4 ov;
    ov.x = ca*xv.x + cb*yv.x + cg*acc[um][0];
    ov.y = ca*xv.y + cb*yv.y + cg*acc[um][1];
    ov.z = ca*xv.z + cb*yv.z + cg*acc[um][2];
    ov.w = ca*xv.w + cb*yv.w + cg*acc[um][3];
    *(float4*)&X[idx] = ov;
  }
}

// -------- transpose X[bh*3+1] (dw1 carried transposed) into XT[bh] --------
__global__ __launch_bounds__(256) void transpose_x1(const float* __restrict__ X,
                                                    float* __restrict__ XT)
{
  __shared__ float tile[64][65];
  const int b = blockIdx.x;
  const int ct = b & 7, rt = (b >> 3) & 7, bh = b >> 6;
  const float* src = X + ((size_t)(bh*3 + 1))*DI_*DD;
  float* dst = XT + (size_t)bh*DI_*DD;
  const int r0 = rt*64, c0 = ct*64;
  const int lr = threadIdx.x >> 4, lc = (threadIdx.x & 15) << 2;
  #pragma unroll
  for (int i = 0; i < 4; ++i) {
    int row = lr + i*16;
    float4 vv = *(const float4*)&src[(size_t)(r0 + row)*DD + c0 + lc];
    tile[row][lc+0]=vv.x; tile[row][lc+1]=vv.y; tile[row][lc+2]=vv.z; tile[row][lc+3]=vv.w;
  }
  __syncthreads();
  #pragma unroll
  for (int i = 0; i < 4; ++i) {
    int row = lr + i*16;
    float4 vv = make_float4(tile[lc+0][row], tile[lc+1][row], tile[lc+2][row], tile[lc+3][row]);
    *(float4*)&dst[(size_t)(c0 + row)*DD + r0 + lc] = vv;
  }
}

// -------- weight update + row-norm rescale: wave per row --------
__global__ __launch_bounds__(256) void update_kernel(
    const float* __restrict__ X, const float* __restrict__ XT,
    float* __restrict__ wm, float* __restrict__ wc,
    const float* __restrict__ wn, const float* __restrict__ mli, int c)
{
  const int gr = blockIdx.x*4 + (threadIdx.x >> 6);
  const int lane = threadIdx.x & 63;
  const int mat = gr >> 9, i = gr & 511;
  const int bh = mat / 3, w = mat - bh*3;
  const float* xrow = (w == 1) ? (XT + ((size_t)bh*512 + i)*512)
                               : (X  + (size_t)mat*DI_*DD + (size_t)i*512);
  float* wmrow = wm + ((size_t)w*BH + bh)*DI_*DD + (size_t)i*512;
  float* wcrow = wc + ((size_t)w*BH + bh)*DI_*DD + (size_t)i*512;
  const float ml = mli[bh*NUP + c];
  float vreg[8];
  float ss = 0.f;
  #pragma unroll
  for (int u = 0; u < 8; ++u) {
    int col = lane + 64*u;
    float nv = wmrow[col] + xrow[col]*ml;
    vreg[u] = nv; ss += nv*nv;
    wmrow[col] = nv;
  }
  #pragma unroll
  for (int off = 32; off > 0; off >>= 1) ss += __shfl_xor(ss, off, 64);
  const float scale = wn[w*4096 + bh*512 + i] / (sqrtf(ss) + 1e-5f);
  #pragma unroll
  for (int u = 0; u < 8; ++u) wcrow[lane + 64*u] = vreg[u]*scale;
}

// -------- initial per-row norms of w0/w1/w2 --------
__global__ __launch_bounds__(256) void wnorm_kernel(
    const float* __restrict__ w0, const float* __restrict__ w1,
    const float* __restrict__ w2, float* __restrict__ wn)
{
  const int gr = blockIdx.x*4 + (threadIdx.x >> 6);
  const int lane = threadIdx.x & 63;
  const int w = gr >> 12, bh = (gr >> 9) & 7, i = gr & 511;
  const float* src = (w==0 ? w0 : (w==1 ? w1 : w2)) + ((size_t)bh*512 + i)*512;
  float ss = 0.f;
  #pragma unroll
  for (int u = 0; u < 8; ++u) { float x = src[lane + 64*u]; ss += x*x; }
  #pragma unroll
  for (int off = 32; off > 0; off >>= 1) ss += __shfl_xor(ss, off, 64);
  if (lane == 0) wn[gr] = sqrtf(ss);
}

// -------- per-(bh,chunk) scalars: m_i = mean(momentum), ml_i = sum(muon)/cs --------
__global__ __launch_bounds__(64) void scalars_kernel(
    const float* __restrict__ mom, const float* __restrict__ mlr,
    float* __restrict__ mi, float* __restrict__ mli)
{
  const int b = blockIdx.x;
  const int bh = b / NUP, c = b % NUP;
  const int lane = threadIdx.x;
  const float* mp = mom + (size_t)bh*SEQT + (size_t)c*CS_;
  const float* lp = mlr + (size_t)bh*SEQT + (size_t)c*CS_;
  float s1 = 0.f, s2 = 0.f;
  #pragma unroll
  for (int u = 0; u < 4; ++u) { s1 += mp[lane + 64*u]; s2 += lp[lane + 64*u]; }
  #pragma unroll
  for (int off = 32; off > 0; off >>= 1) {
    s1 += __shfl_xor(s1, off, 64);
    s2 += __shfl_xor(s2, off, 64);
  }
  if (lane == 0) { mi[bh*NUP + c] = s1/256.f; mli[bh*NUP + c] = s2/256.f; }
}

static const float NSC[5][3] = {
  {4.0848f, -6.8946f, 2.9270f},
  {3.9505f, -6.3029f, 2.6377f},
  {3.7418f, -5.5913f, 2.3037f},
  {2.8769f, -3.1427f, 1.2046f},
  {2.8366f, -3.0525f, 1.2012f}};

extern "C" void kernel_launch(void* const* d_in, const int* in_sizes, int n_in,
                              void* d_out, int out_size, void* d_ws, size_t ws_size,
                              hipStream_t stream)
{
  (void)in_sizes; (void)n_in; (void)out_size; (void)ws_size;
  const float* w0  = (const float*)d_in[0];
  const float* w1  = (const float*)d_in[1];
  const float* w2  = (const float*)d_in[2];
  const float* q   = (const float*)d_in[3];
  const float* k   = (const float*)d_in[4];
  const float* v   = (const float*)d_in[5];
  const float* lr0 = (const float*)d_in[6];
  const float* lr1 = (const float*)d_in[7];
  const float* lr2 = (const float*)d_in[8];
  const float* mom = (const float*)d_in[9];
  const float* mlr = (const float*)d_in[10];
  float* out = (float*)d_out;
  float* ws  = (float*)d_ws;

  float* WM  = ws + OFF_WM;
  float* WC  = ws + OFF_WC;
  float* DM  = ws + OFF_DM;
  float* X   = ws + OFF_X;
  float* A   = ws + OFF_A;
  float* SQ  = ws + OFF_SQ;
  float* GBA = ws + OFF_GBA;
  float* HBMb= ws + OFF_HBM;
  float* HID = ws + OFF_HID;
  float* DGB = ws + OFF_DGB;
  float* DHB = ws + OFF_DHB;
  float* Y   = ws + OFF_Y;     // overlay on SQ..DHB (dead during NS)
  float* FRO = ws + OFF_FRO;
  float* MI  = ws + OFF_MI;
  float* MLI = ws + OFF_MLI;
  float* WN  = ws + OFF_WN;

  for (int w = 0; w < 3; ++w) {
    const float* src = (w==0 ? w0 : (w==1 ? w1 : w2));
    hipMemcpyAsync(WM + (size_t)w*SZ_W1, src, SZ_W1*sizeof(float),
                   hipMemcpyDeviceToDevice, stream);
    hipMemcpyAsync(WC + (size_t)w*SZ_W1, src, SZ_W1*sizeof(float),
                   hipMemcpyDeviceToDevice, stream);
  }
  hipMemsetAsync(DM, 0, SZ_W*sizeof(float), stream);
  hipMemsetAsync(FRO, 0, 360*sizeof(float), stream);
  wnorm_kernel<<<3072, 256, 0, stream>>>(w0, w1, w2, WN);
  scalars_kernel<<<BH*NUP, 64, 0, stream>>>(mom, mlr, MI, MLI);

  for (int c = 0; c < NUP; ++c) {
    fwd_kernel<<<512, 256, 0, stream>>>(WC, WC + 2*SZ_W1, q, k, SQ, GBA, HBMb, HID, c, 2);
    out_kernel<<<256, 256, 0, stream>>>(WC + SZ_W1, SQ, out, c);
    dh_kernel<<<256, 256, 0, stream>>>(v, WC + SZ_W1, GBA, HBMb, DGB, DHB, c);
    dw_kernel<<<1536, 256, 0, stream>>>(DGB, DHB, HID, k, v, lr0, lr1, lr2,
                                        DM, X, MI, FRO + c*24, c);
    ns_scale_kernel<<<6144, 256, 0, stream>>>(X, FRO + c*24);
    for (int s = 0; s < 5; ++s) {
      nsA_kernel<<<1536, 256, 0, stream>>>(X, A);
      nsY_kernel<<<1536, 256, 0, stream>>>(A, X, Y);
      nsZ_kernel<<<1536, 256, 0, stream>>>(A, Y, X, NSC[s][0], NSC[s][1], NSC[s][2]);
    }
    transpose_x1<<<512, 256, 0, stream>>>(X, Y);
    update_kernel<<<3072, 256, 0, stream>>>(X, Y, WM, WC, WN, MLI, c);
  }
  // final forward-only chunk with last normalized weights
  fwd_kernel<<<256, 256, 0, stream>>>(WC, WC + 2*SZ_W1, q, k, SQ, GBA, HBMb, HID, NUP, 1);
  out_kernel<<<256, 256, 0, stream>>>(WC + SZ_W1, SQ, out, NUP);
}

// Round 2
// 16055.829 us; speedup vs baseline: 1.4737x; 1.4737x over previous
//
#include <hip/hip_runtime.h>
#include <math.h>

#define BH   8
#define SEQT 4096
#define DD   512
#define DI_  512
#define CS_  256
#define NUP  15

typedef unsigned short u16;
typedef float f32x16 __attribute__((ext_vector_type(16)));
typedef short v8s    __attribute__((ext_vector_type(8)));

__device__ __forceinline__ float sigm(float x){ return 1.0f/(1.0f+expf(-x)); }

__device__ __forceinline__ float bf2f(u16 h){
  union{unsigned u; float f;} v; v.u = ((unsigned)h)<<16; return v.f;
}
__device__ __forceinline__ u16 f2bf_rn(float x){
  union{float f; unsigned u;} v; v.f = x;
  unsigned r = (v.u + 0x7fffu + ((v.u>>16)&1u)) >> 16;
  return (u16)r;
}
__device__ __forceinline__ void split_bf(float x, u16 &h, u16 &l){
  h = f2bf_rn(x);
  l = f2bf_rn(x - bf2f(h));
}

// ============================ PRIMARY (MFMA) PATH ============================
// All GEMMs are NT: C[m][n] = sum_k A[m][k]*B[n][k], A/B pre-split bf16 hi/lo.
// 128x128 block tile, 4 waves (2x2), each wave 2x2 frags of 32x32x16 MFMA,
// 3 products per frag (hh, hl, lh).

struct Smem {
  u16 Ah[128][40]; u16 Al[128][40];
  u16 Bh[128][40]; u16 Bl[128][40];
};

#define TIDS \
  const int tid = threadIdx.x; const int lane = tid & 63; \
  const int wv = tid >> 6, wm = wv & 1, wn = wv >> 1; \
  const int l31 = lane & 31, hv = lane >> 5;

__device__ __forceinline__ void mm_core(
    const u16* Ah, const u16* Al, int lda, int m0,
    const u16* Bh, const u16* Bl, int ldb, int n0,
    int K, Smem& sm, f32x16 (&acc)[2][2])
{
  TIDS;
  const int sr = tid >> 1, sc = (tid & 1) << 4;
  const u16* pAh = Ah + (size_t)(m0 + sr) * lda + sc;
  const u16* pAl = Al + (size_t)(m0 + sr) * lda + sc;
  const u16* pBh = Bh + (size_t)(n0 + sr) * ldb + sc;
  const u16* pBl = Bl + (size_t)(n0 + sr) * ldb + sc;
  for (int kb = 0; kb < K; kb += 32) {
    int4 a0 = *(const int4*)(pAh + kb);
    int4 a1 = *(const int4*)(pAh + kb + 8);
    int4 a2 = *(const int4*)(pAl + kb);
    int4 a3 = *(const int4*)(pAl + kb + 8);
    int4 b0 = *(const int4*)(pBh + kb);
    int4 b1 = *(const int4*)(pBh + kb + 8);
    int4 b2 = *(const int4*)(pBl + kb);
    int4 b3 = *(const int4*)(pBl + kb + 8);
    __syncthreads();
    *(int4*)&sm.Ah[sr][sc] = a0; *(int4*)&sm.Ah[sr][sc+8] = a1;
    *(int4*)&sm.Al[sr][sc] = a2; *(int4*)&sm.Al[sr][sc+8] = a3;
    *(int4*)&sm.Bh[sr][sc] = b0; *(int4*)&sm.Bh[sr][sc+8] = b1;
    *(int4*)&sm.Bl[sr][sc] = b2; *(int4*)&sm.Bl[sr][sc+8] = b3;
    __syncthreads();
    #pragma unroll
    for (int h = 0; h < 2; ++h) {
      v8s afh[2], afl[2], bfh[2], bfl[2];
      const int col = h*16 + hv*8;
      #pragma unroll
      for (int i = 0; i < 2; ++i) {
        afh[i] = *(const v8s*)&sm.Ah[wm*64 + i*32 + l31][col];
        afl[i] = *(const v8s*)&sm.Al[wm*64 + i*32 + l31][col];
        bfh[i] = *(const v8s*)&sm.Bh[wn*64 + i*32 + l31][col];
        bfl[i] = *(const v8s*)&sm.Bl[wn*64 + i*32 + l31][col];
      }
      #pragma unroll
      for (int i = 0; i < 2; ++i)
        #pragma unroll
        for (int j = 0; j < 2; ++j) {
          acc[i][j] = __builtin_amdgcn_mfma_f32_32x32x16_bf16(afh[i], bfh[j], acc[i][j], 0, 0, 0);
          acc[i][j] = __builtin_amdgcn_mfma_f32_32x32x16_bf16(afh[i], bfl[j], acc[i][j], 0, 0, 0);
          acc[i][j] = __builtin_amdgcn_mfma_f32_32x32x16_bf16(afl[i], bfh[j], acc[i][j], 0, 0, 0);
        }
    }
  }
}

#define EPI_BEGIN \
  _Pragma("unroll") for (int i = 0; i < 2; ++i) { \
  _Pragma("unroll") for (int j = 0; j < 2; ++j) { \
  _Pragma("unroll") for (int rg = 0; rg < 16; ++rg) { \
    const int gr = m0 + wm*64 + i*32 + (rg&3) + 8*(rg>>2) + 4*hv; \
    const int gc = n0 + wn*64 + j*32 + l31; \
    const float av = acc[i][j][rg];
#define EPI_END }}}

// ---- fwd: P[t][j] = chunk[t][d] . W[j][d] ; 4 combos (q/k x w0/w2) ----
__global__ __launch_bounds__(256) void k_fwd(
    const u16* QcH, const u16* QcL, const u16* KcH, const u16* KcL,
    const u16* WCH, const u16* WCL,
    float* P0q, float* P2q, float* GBA, float* HBMa)
{
  __shared__ Smem sm;
  const int bx = blockIdx.x;
  const int nt = bx & 3, mt = (bx >> 2) & 1, bh = (bx >> 3) & 7, combo = bx >> 6;
  const int m0 = mt*128, n0 = nt*128;
  const u16* Ah = (combo < 2 ? QcH : KcH) + (size_t)bh*131072;
  const u16* Al = (combo < 2 ? QcL : KcL) + (size_t)bh*131072;
  const int w = (combo & 1) ? 2 : 0;
  const u16* Bh = WCH + ((size_t)(w*8 + bh))*262144;
  const u16* Bl = WCL + ((size_t)(w*8 + bh))*262144;
  float* dst = (combo==0 ? P0q : combo==1 ? P2q : combo==2 ? GBA : HBMa) + (size_t)bh*131072;
  f32x16 acc[2][2] = {};
  mm_core(Ah, Al, 512, m0, Bh, Bl, 512, n0, 512, sm, acc);
  TIDS;
  EPI_BEGIN
    dst[(size_t)gr*512 + gc] = av;
  EPI_END
}

// ---- out (flag0): O[t][d] = SQ[t][j].W1[d][j] ; dh (flag1): E[t][j]=V[t][d].W1T[j][d] ----
__global__ __launch_bounds__(256) void k_outdh(
    const u16* SQH, const u16* SQL, const u16* WCH, const u16* WCL,
    const u16* VcH, const u16* VcL, const u16* W1TH, const u16* W1TL,
    const float* GBA, const float* HBMa, float* DGB, float* DHB,
    float* out, int c)
{
  __shared__ Smem sm;
  const int bx = blockIdx.x;
  const int flag = bx >> 6;
  const int r = bx & 63;
  const int nt = r & 3, mt = (r >> 2) & 1, bh = r >> 3;
  const int m0 = mt*128, n0 = nt*128;
  f32x16 acc[2][2] = {};
  TIDS;
  if (flag == 0) {
    mm_core(SQH + (size_t)bh*131072, SQL + (size_t)bh*131072, 512, m0,
            WCH + ((size_t)(8 + bh))*262144, WCL + ((size_t)(8 + bh))*262144, 512, n0,
            512, sm, acc);
    float* o = out + ((size_t)bh*SEQT + (size_t)c*CS_) * DD;
    EPI_BEGIN
      o[(size_t)gr*512 + gc] = av;
    EPI_END
  } else {
    mm_core(VcH + (size_t)bh*131072, VcL + (size_t)bh*131072, 512, m0,
            W1TH + (size_t)bh*262144, W1TL + (size_t)bh*262144, 512, n0,
            512, sm, acc);
    EPI_BEGIN
      size_t gi = (size_t)bh*131072 + (size_t)gr*512 + gc;
      float g = GBA[gi], hb = HBMa[gi];
      float s = sigm(g);
      DHB[gi] = av * g * s;
      float dgate = av * hb;
      DGB[gi] = dgate * s * (1.f + g*(1.f - s));
    EPI_END
  }
}

// ---- dw: C[j][d] = At[j][t].Bt[d][t], K=256; momentum + X + fro ----
__global__ __launch_bounds__(256) void k_dw(
    const u16* DGBTH, const u16* DGBTL, const u16* DHBTH, const u16* DHBTL,
    const u16* HIDTH, const u16* HIDTL,
    const u16* KTH, const u16* KTL, const u16* VTH, const u16* VTL,
    float* DM, float* X, const float* MI, float* fro, int c)
{
  __shared__ Smem sm;
  __shared__ float red[4];
  const int bx = blockIdx.x;
  const int nt = bx & 3, mt = (bx >> 2) & 3, bh = (bx >> 4) & 7, w = bx >> 7;
  const int m0 = mt*128, n0 = nt*128;
  const u16* Ah = (w==0 ? DGBTH : w==1 ? HIDTH : DHBTH) + (size_t)bh*131072;
  const u16* Al = (w==0 ? DGBTL : w==1 ? HIDTL : DHBTL) + (size_t)bh*131072;
  const u16* Bh = (w==1 ? VTH : KTH) + (size_t)bh*131072;
  const u16* Bl = (w==1 ? VTL : KTL) + (size_t)bh*131072;
  f32x16 acc[2][2] = {};
  mm_core(Ah, Al, 256, m0, Bh, Bl, 256, n0, 256, sm, acc);
  TIDS;
  const float m_i = MI[bh*NUP + c];
  const int mat = bh*3 + w;
  float fs = 0.f;
  EPI_BEGIN
    size_t di = ((size_t)(w*8 + bh))*262144 + (size_t)gr*512 + gc;
    float dv = av + DM[di]*m_i;
    DM[di] = dv;
    X[(size_t)mat*262144 + (size_t)gr*512 + gc] = dv;
    fs += dv*dv;
  EPI_END
  #pragma unroll
  for (int off = 32; off > 0; off >>= 1) fs += __shfl_down(fs, off, 64);
  if ((tid & 63) == 0) red[tid >> 6] = fs;
  __syncthreads();
  if (tid == 0) atomicAdd(&fro[mat], red[0]+red[1]+red[2]+red[3]);
}

// ---- NS: Amat = NT(X, X) -> AH/AL ----
__global__ __launch_bounds__(256) void k_nsA(
    const u16* XsH, const u16* XsL, u16* AoH, u16* AoL)
{
  __shared__ Smem sm;
  const int bx = blockIdx.x;
  const int nt = bx & 3, mt = (bx >> 2) & 3, mat = bx >> 4;
  const int m0 = mt*128, n0 = nt*128;
  const size_t mb = (size_t)mat*262144;
  f32x16 acc[2][2] = {};
  mm_core(XsH + mb, XsL + mb, 512, m0, XsH + mb, XsL + mb, 512, n0, 512, sm, acc);
  TIDS;
  EPI_BEGIN
    size_t fi = mb + (size_t)gr*512 + gc;
    u16 hh, ll; split_bf(av, hh, ll);
    AoH[fi] = hh; AoL[fi] = ll;
  EPI_END
}

// ---- NS: Bmat = cb*A + cc*NT(A,A) -> S3 (A symmetric) ----
__global__ __launch_bounds__(256) void k_nsB(
    const u16* AsH, const u16* AsL, u16* BoH, u16* BoL, float cb, float cc)
{
  __shared__ Smem sm;
  const int bx = blockIdx.x;
  const int nt = bx & 3, mt = (bx >> 2) & 3, mat = bx >> 4;
  const int m0 = mt*128, n0 = nt*128;
  const size_t mb = (size_t)mat*262144;
  f32x16 acc[2][2] = {};
  mm_core(AsH + mb, AsL + mb, 512, m0, AsH + mb, AsL + mb, 512, n0, 512, sm, acc);
  TIDS;
  EPI_BEGIN
    size_t fi = mb + (size_t)gr*512 + gc;
    float af = bf2f(AsH[fi]) + bf2f(AsL[fi]);
    float bm = cb*af + cc*av;
    u16 hh, ll; split_bf(bm, hh, ll);
    BoH[fi] = hh; BoL[fi] = ll;
  EPI_END
}

// ---- NS: X' = ca*X + Bmat @ X  (B-op transpose-staged from X hi/lo) ----
struct SmemZ {
  u16 Ah[128][40]; u16 Al[128][40];
  unsigned B2h[128][20]; unsigned B2l[128][20];
};

__global__ __launch_bounds__(256) void k_nsZ(
    const u16* BmH, const u16* BmL, const u16* XsH, const u16* XsL,
    float* X, u16* XnH, u16* XnL, float ca)
{
  __shared__ SmemZ sm;
  const int bx = blockIdx.x;
  const int nt = bx & 3, mt = (bx >> 2) & 3, mat = bx >> 4;
  const int m0 = mt*128, n0 = nt*128;
  const size_t mb = (size_t)mat*262144;
  TIDS;
  const int sr = tid >> 1, sc = (tid & 1) << 4;
  const int rp = tid & 15, cq = tid >> 4;
  const u16* pAh = BmH + mb + (size_t)(m0 + sr)*512 + sc;
  const u16* pAl = BmL + mb + (size_t)(m0 + sr)*512 + sc;
  const u16* pXh = XsH + mb;
  const u16* pXl = XsL + mb;
  f32x16 acc[2][2] = {};
  for (int kb = 0; kb < 512; kb += 32) {
    int4 a0 = *(const int4*)(pAh + kb);
    int4 a1 = *(const int4*)(pAh + kb + 8);
    int4 a2 = *(const int4*)(pAl + kb);
    int4 a3 = *(const int4*)(pAl + kb + 8);
    const u16* q0 = pXh + (size_t)(kb + 2*rp)*512 + n0 + 8*cq;
    const u16* q1 = pXl + (size_t)(kb + 2*rp)*512 + n0 + 8*cq;
    union { int4 v; u16 s[8]; } uh0, uh1, ul0, ul1;
    uh0.v = *(const int4*)q0;
    uh1.v = *(const int4*)(q0 + 512);
    ul0.v = *(const int4*)q1;
    ul1.v = *(const int4*)(q1 + 512);
    __syncthreads();
    *(int4*)&sm.Ah[sr][sc] = a0; *(int4*)&sm.Ah[sr][sc+8] = a1;
    *(int4*)&sm.Al[sr][sc] = a2; *(int4*)&sm.Al[sr][sc+8] = a3;
    #pragma unroll
    for (int e = 0; e < 8; ++e) {
      sm.B2h[8*cq + e][rp] = (unsigned)uh0.s[e] | ((unsigned)uh1.s[e] << 16);
      sm.B2l[8*cq + e][rp] = (unsigned)ul0.s[e] | ((unsigned)ul1.s[e] << 16);
    }
    __syncthreads();
    #pragma unroll
    for (int h = 0; h < 2; ++h) {
      v8s afh[2], afl[2], bfh[2], bfl[2];
      const int colA = h*16 + hv*8;
      const int colB = 8*h + 4*hv;
      #pragma unroll
      for (int i = 0; i < 2; ++i) {
        afh[i] = *(const v8s*)&sm.Ah[wm*64 + i*32 + l31][colA];
        afl[i] = *(const v8s*)&sm.Al[wm*64 + i*32 + l31][colA];
        bfh[i] = *(const v8s*)&sm.B2h[wn*64 + i*32 + l31][colB];
        bfl[i] = *(const v8s*)&sm.B2l[wn*64 + i*32 + l31][colB];
      }
      #pragma unroll
      for (int i = 0; i < 2; ++i)
        #pragma unroll
        for (int j = 0; j < 2; ++j) {
          acc[i][j] = __builtin_amdgcn_mfma_f32_32x32x16_bf16(afh[i], bfh[j], acc[i][j], 0, 0, 0);
          acc[i][j] = __builtin_amdgcn_mfma_f32_32x32x16_bf16(afh[i], bfl[j], acc[i][j], 0, 0, 0);
          acc[i][j] = __builtin_amdgcn_mfma_f32_32x32x16_bf16(afl[i], bfh[j], acc[i][j], 0, 0, 0);
        }
    }
  }
  EPI_BEGIN
    size_t fi = mb + (size_t)gr*512 + gc;
    float nv = ca*X[fi] + av;
    X[fi] = nv;
    u16 hh, ll; split_bf(nv, hh, ll);
    XnH[fi] = hh; XnL[fi] = ll;
  EPI_END
}

// ---- transpose+convert: fp32 src [R=256][C=512] (opt row scale) -> hi/lo [C][R] ----
__global__ __launch_bounds__(256) void k_tc(
    const float* DGB, const float* DHB, const float* HID,
    const float* kin, const float* vin,
    const float* lr0, const float* lr1, const float* lr2,
    u16* DGBTH, u16* DGBTL, u16* DHBTH, u16* DHBTL, u16* HIDTH, u16* HIDTL,
    u16* KTH, u16* KTL, u16* VTH, u16* VTL, int c)
{
  __shared__ u16 Th[64][72], Tl[64][72];
  const int bx = blockIdx.x;
  const int tile = bx & 31, bh = (bx >> 5) & 7, job = bx >> 8;
  const int rt = tile >> 3, ct = tile & 7;
  const int r0 = rt*64, c0 = ct*64;
  const float* src; const float* scale; u16* dH; u16* dL;
  size_t choff = (size_t)bh*2097152 + (size_t)c*131072;
  size_t aoff  = (size_t)bh*131072;
  if      (job == 0) { src = DGB + aoff; scale = lr0 + bh*SEQT + c*CS_; dH = DGBTH + aoff; dL = DGBTL + aoff; }
  else if (job == 1) { src = DHB + aoff; scale = lr2 + bh*SEQT + c*CS_; dH = DHBTH + aoff; dL = DHBTL + aoff; }
  else if (job == 2) { src = HID + aoff; scale = lr1 + bh*SEQT + c*CS_; dH = HIDTH + aoff; dL = HIDTL + aoff; }
  else if (job == 3) { src = kin + choff; scale = nullptr; dH = KTH + aoff; dL = KTL + aoff; }
  else               { src = vin + choff; scale = nullptr; dH = VTH + aoff; dL = VTL + aoff; }
  const int tid = threadIdx.x;
  const int rl = tid >> 4;
  const int cl = (tid & 15) << 2;
  #pragma unroll
  for (int it = 0; it < 4; ++it) {
    int row = rl + it*16;
    float sc = scale ? scale[r0 + row] : 1.0f;
    float4 v = *(const float4*)&src[(size_t)(r0 + row)*512 + c0 + cl];
    u16 h, l;
    split_bf(v.x*sc, h, l); Th[cl+0][row] = h; Tl[cl+0][row] = l;
    split_bf(v.y*sc, h, l); Th[cl+1][row] = h; Tl[cl+1][row] = l;
    split_bf(v.z*sc, h, l); Th[cl+2][row] = h; Tl[cl+2][row] = l;
    split_bf(v.w*sc, h, l); Th[cl+3][row] = h; Tl[cl+3][row] = l;
  }
  __syncthreads();
  const int c2 = tid >> 2;
  const int rg = (tid & 3) << 4;
  size_t dbase = (size_t)(c0 + c2)*256 + r0 + rg;
  *(int4*)&dH[dbase]     = *(int4*)&Th[c2][rg];
  *(int4*)&dH[dbase + 8] = *(int4*)&Th[c2][rg + 8];
  *(int4*)&dL[dbase]     = *(int4*)&Tl[c2][rg];
  *(int4*)&dL[dbase + 8] = *(int4*)&Tl[c2][rg + 8];
}

// ---- transpose bf16 hi/lo: W1T[j][d] <- WC w1 [d][j] ----
__global__ __launch_bounds__(256) void k_tb(
    const u16* WCH, const u16* WCL, u16* W1TH, u16* W1TL)
{
  __shared__ u16 Th[64][72], Tl[64][72];
  const int bx = blockIdx.x;
  const int ct = bx & 7, rt = (bx >> 3) & 7, bh = bx >> 6;
  const int r0 = rt*64, c0 = ct*64;
  const u16* sH = WCH + ((size_t)(8 + bh))*262144;
  const u16* sL = WCL + ((size_t)(8 + bh))*262144;
  const int tid = threadIdx.x;
  const int rl = tid >> 2;
  const int cg = (tid & 3) << 4;
  {
    union { int4 v[2]; u16 s[16]; } ah, al;
    ah.v[0] = *(const int4*)&sH[(size_t)(r0 + rl)*512 + c0 + cg];
    ah.v[1] = *(const int4*)&sH[(size_t)(r0 + rl)*512 + c0 + cg + 8];
    al.v[0] = *(const int4*)&sL[(size_t)(r0 + rl)*512 + c0 + cg];
    al.v[1] = *(const int4*)&sL[(size_t)(r0 + rl)*512 + c0 + cg + 8];
    #pragma unroll
    for (int e = 0; e < 16; ++e) { Th[cg + e][rl] = ah.s[e]; Tl[cg + e][rl] = al.s[e]; }
  }
  __syncthreads();
  const int c2 = tid >> 2;
  const int rg = (tid & 3) << 4;
  size_t dbase = (size_t)bh*262144 + (size_t)(c0 + c2)*512 + r0 + rg;
  *(int4*)&W1TH[dbase]     = *(int4*)&Th[c2][rg];
  *(int4*)&W1TH[dbase + 8] = *(int4*)&Th[c2][rg + 8];
  *(int4*)&W1TL[dbase]     = *(int4*)&Tl[c2][rg];
  *(int4*)&W1TL[dbase + 8] = *(int4*)&Tl[c2][rg + 8];
}

// ---- convert q,k,v chunk slices -> hi/lo ----
__global__ __launch_bounds__(256) void k_cvt_qkv(
    const float* q, const float* k, const float* v,
    u16* QcH, u16* QcL, u16* KcH, u16* KcL, u16* VcH, u16* VcL, int c)
{
  const int gid = blockIdx.x*256 + threadIdx.x;
  const size_t e8 = (size_t)gid * 8;
  const int arr = (int)(e8 / 1048576);
  const size_t r = e8 % 1048576;
  const int bh = (int)(r / 131072);
  const size_t off = r % 131072;
  const float* src = (arr==0 ? q : arr==1 ? k : v) + (size_t)bh*2097152 + (size_t)c*131072 + off;
  u16* dH = (arr==0 ? QcH : arr==1 ? KcH : VcH) + r;
  u16* dL = (arr==0 ? QcL : arr==1 ? KcL : VcL) + r;
  float4 v0 = *(const float4*)src;
  float4 v1 = *(const float4*)(src + 4);
  ushort4 h0, l0, h1, l1;
  split_bf(v0.x, h0.x, l0.x); split_bf(v0.y, h0.y, l0.y);
  split_bf(v0.z, h0.z, l0.z); split_bf(v0.w, h0.w, l0.w);
  split_bf(v1.x, h1.x, l1.x); split_bf(v1.y, h1.y, l1.y);
  split_bf(v1.z, h1.z, l1.z); split_bf(v1.w, h1.w, l1.w);
  *(ushort4*)(dH)     = h0; *(ushort4*)(dH + 4) = h1;
  *(ushort4*)(dL)     = l0; *(ushort4*)(dL + 4) = l1;
}

// ---- convert initial weights -> WCH/WCL ----
__global__ __launch_bounds__(256) void k_cvt_w(
    const float* w0, const float* w1, const float* w2, u16* WCH, u16* WCL)
{
  const int gid = blockIdx.x*256 + threadIdx.x;
  const size_t e8 = (size_t)gid * 8;
  const int w = (int)(e8 / 2097152);
  const size_t off = e8 % 2097152;
  const float* src = (w==0 ? w0 : w==1 ? w1 : w2) + off;
  u16* dH = WCH + (size_t)w*2097152 + off;
  u16* dL = WCL + (size_t)w*2097152 + off;
  float4 v0 = *(const float4*)src;
  float4 v1 = *(const float4*)(src + 4);
  ushort4 h0, l0, h1, l1;
  split_bf(v0.x, h0.x, l0.x); split_bf(v0.y, h0.y, l0.y);
  split_bf(v0.z, h0.z, l0.z); split_bf(v0.w, h0.w, l0.w);
  split_bf(v1.x, h1.x, l1.x); split_bf(v1.y, h1.y, l1.y);
  split_bf(v1.z, h1.z, l1.z); split_bf(v1.w, h1.w, l1.w);
  *(ushort4*)(dH)     = h0; *(ushort4*)(dH + 4) = h1;
  *(ushort4*)(dL)     = l0; *(ushort4*)(dL + 4) = l1;
}

// ---- combine: job0 SQ=silu(P0q)*P2q -> hi/lo ; job1 HID=silu(GBA)*HBM fp32 ----
__global__ __launch_bounds__(256) void k_combine(
    const float* P0q, const float* P2q, const float* GBA, const float* HBMa,
    u16* SQH, u16* SQL, float* HID)
{
  const int bx = blockIdx.x;
  const int flag = bx >> 10;
  const int i4 = (bx & 1023)*256 + threadIdx.x;
  if (flag == 0) {
    float4 p0 = ((const float4*)P0q)[i4];
    float4 p2 = ((const float4*)P2q)[i4];
    float4 s;
    s.x = p0.x*sigm(p0.x)*p2.x; s.y = p0.y*sigm(p0.y)*p2.y;
    s.z = p0.z*sigm(p0.z)*p2.z; s.w = p0.w*sigm(p0.w)*p2.w;
    ushort4 h, l;
    split_bf(s.x, h.x, l.x); split_bf(s.y, h.y, l.y);
    split_bf(s.z, h.z, l.z); split_bf(s.w, h.w, l.w);
    ((ushort4*)SQH)[i4] = h; ((ushort4*)SQL)[i4] = l;
  } else {
    float4 g = ((const float4*)GBA)[i4];
    float4 hb = ((const float4*)HBMa)[i4];
    float4 o;
    o.x = g.x*sigm(g.x)*hb.x; o.y = g.y*sigm(g.y)*hb.y;
    o.z = g.z*sigm(g.z)*hb.z; o.w = g.w*sigm(g.w)*hb.w;
    ((float4*)HID)[i4] = o;
  }
}

// ---- X *= 1/(||X||_F+1e-7); also write hi/lo into step-0 slot ----
__global__ __launch_bounds__(256) void k_scale(
    float* X, u16* XH, u16* XL, const float* fro)
{
  const int gid = blockIdx.x*256 + threadIdx.x;
  const int mat = gid >> 16;
  float inv = 1.0f/(sqrtf(fro[mat]) + 1e-7f);
  float4 v = ((float4*)X)[gid];
  v.x *= inv; v.y *= inv; v.z *= inv; v.w *= inv;
  ((float4*)X)[gid] = v;
  ushort4 h, l;
  split_bf(v.x, h.x, l.x); split_bf(v.y, h.y, l.y);
  split_bf(v.z, h.z, l.z); split_bf(v.w, h.w, l.w);
  ((ushort4*)XH)[gid] = h; ((ushort4*)XL)[gid] = l;
}

// ---- weight update + rownorm rescale -> WM fp32, WC hi/lo ----
__global__ __launch_bounds__(256) void k_update2(
    const float* X, const float* XT1, float* wm, u16* WCH, u16* WCL,
    const float* wn, const float* mli, int c)
{
  const int gr = blockIdx.x*4 + (threadIdx.x >> 6);
  const int lane = threadIdx.x & 63;
  const int mat = gr >> 9, i = gr & 511;
  const int bh = mat / 3, w = mat - bh*3;
  const float* xrow = (w == 1) ? (XT1 + ((size_t)bh*512 + i)*512)
                               : (X   + (size_t)mat*262144 + (size_t)i*512);
  float* wmrow = wm + ((size_t)w*BH + bh)*262144 + (size_t)i*512;
  const float ml = mli[bh*NUP + c];
  float vreg[8];
  float ss = 0.f;
  #pragma unroll
  for (int u = 0; u < 8; ++u) {
    int col = lane + 64*u;
    float nv = wmrow[col] + xrow[col]*ml;
    vreg[u] = nv; ss += nv*nv;
    wmrow[col] = nv;
  }
  #pragma unroll
  for (int off = 32; off > 0; off >>= 1) ss += __shfl_xor(ss, off, 64);
  const float scale = wn[w*4096 + bh*512 + i] / (sqrtf(ss) + 1e-5f);
  size_t wb = ((size_t)w*BH + bh)*262144 + (size_t)i*512;
  #pragma unroll
  for (int u = 0; u < 8; ++u) {
    u16 h, l;
    split_bf(vreg[u]*scale, h, l);
    WCH[wb + lane + 64*u] = h;
    WCL[wb + lane + 64*u] = l;
  }
}

// ---- transpose final X1 (dw1 carried transposed) fp32 ----
__global__ __launch_bounds__(256) void transpose_x1(const float* __restrict__ X,
                                                    float* __restrict__ XT)
{
  __shared__ float tile[64][65];
  const int b = blockIdx.x;
  const int ct = b & 7, rt = (b >> 3) & 7, bh = b >> 6;
  const float* src = X + ((size_t)(bh*3 + 1))*262144;
  float* dst = XT + (size_t)bh*262144;
  const int r0 = rt*64, c0 = ct*64;
  const int lr = threadIdx.x >> 4, lc = (threadIdx.x & 15) << 2;
  #pragma unroll
  for (int i = 0; i < 4; ++i) {
    int row = lr + i*16;
    float4 vv = *(const float4*)&src[(size_t)(r0 + row)*512 + c0 + lc];
    tile[row][lc+0]=vv.x; tile[row][lc+1]=vv.y; tile[row][lc+2]=vv.z; tile[row][lc+3]=vv.w;
  }
  __syncthreads();
  #pragma unroll
  for (int i = 0; i < 4; ++i) {
    int row = lr + i*16;
    float4 vv = make_float4(tile[lc+0][row], tile[lc+1][row], tile[lc+2][row], tile[lc+3][row]);
    *(float4*)&dst[(size_t)(c0 + row)*512 + r0 + lc] = vv;
  }
}

// ---- initial per-row norms of w0/w1/w2 ----
__global__ __launch_bounds__(256) void wnorm_kernel(
    const float* __restrict__ w0, const float* __restrict__ w1,
    const float* __restrict__ w2, float* __restrict__ wn)
{
  const int gr = blockIdx.x*4 + (threadIdx.x >> 6);
  const int lane = threadIdx.x & 63;
  const int w = gr >> 12, bh = (gr >> 9) & 7, i = gr & 511;
  const float* src = (w==0 ? w0 : (w==1 ? w1 : w2)) + ((size_t)bh*512 + i)*512;
  float ss = 0.f;
  #pragma unroll
  for (int u = 0; u < 8; ++u) { float x = src[lane + 64*u]; ss += x*x; }
  #pragma unroll
  for (int off = 32; off > 0; off >>= 1) ss += __shfl_xor(ss, off, 64);
  if (lane == 0) wn[gr] = sqrtf(ss);
}

// ---- per-(bh,chunk) scalars ----
__global__ __launch_bounds__(64) void scalars_kernel(
    const float* __restrict__ mom, const float* __restrict__ mlr,
    float* __restrict__ mi, float* __restrict__ mli)
{
  const int b = blockIdx.x;
  const int bh = b / NUP, c = b % NUP;
  const int lane = threadIdx.x;
  const float* mp = mom + (size_t)bh*SEQT + (size_t)c*CS_;
  const float* lp = mlr + (size_t)bh*SEQT + (size_t)c*CS_;
  float s1 = 0.f, s2 = 0.f;
  #pragma unroll
  for (int u = 0; u < 4; ++u) { s1 += mp[lane + 64*u]; s2 += lp[lane + 64*u]; }
  #pragma unroll
  for (int off = 32; off > 0; off >>= 1) {
    s1 += __shfl_xor(s1, off, 64);
    s2 += __shfl_xor(s2, off, 64);
  }
  if (lane == 0) { mi[bh*NUP + c] = s1/256.f; mli[bh*NUP + c] = s2/256.f; }
}

static const float NSC[5][3] = {
  {4.0848f, -6.8946f, 2.9270f},
  {3.9505f, -6.3029f, 2.6377f},
  {3.7418f, -5.5913f, 2.3037f},
  {2.8769f, -3.1427f, 1.2046f},
  {2.8366f, -3.0525f, 1.2012f}};

// ============================ FALLBACK (fp32) PATH ===========================
#define SZ_W    (3ull*BH*DI_*DD)
#define SZ_W1   ((size_t)BH*DI_*DD)
#define SZ_ACT  ((size_t)BH*DI_*CS_)
#define OFF_WM  0ull
#define OFF_WC  (OFF_WM + SZ_W)
#define OFF_DM  (OFF_WC + SZ_W)
#define OFF_X   (OFF_DM + SZ_W)
#define OFF_A   (OFF_X  + SZ_W)
#define OFF_SQ  (OFF_A  + SZ_W)
#define OFF_GBA (OFF_SQ  + SZ_ACT)
#define OFF_HBM (OFF_GBA + SZ_ACT)
#define OFF_HID (OFF_HBM + SZ_ACT)
#define OFF_DGB (OFF_HID + SZ_ACT)
#define OFF_DHB (OFF_DGB + SZ_ACT)
#define OFF_Y   OFF_SQ
#define OFF_FRO (OFF_DHB + SZ_ACT)
#define OFF_MI  (OFF_FRO + 360)
#define OFF_MLI (OFF_MI  + 120)
#define OFF_WN  (OFF_MLI + 120)

#define FMA44(ACC,AV,BV) do{ \
  ACC[0][0]+=AV.x*BV.x; ACC[0][1]+=AV.x*BV.y; ACC[0][2]+=AV.x*BV.z; ACC[0][3]+=AV.x*BV.w; \
  ACC[1][0]+=AV.y*BV.x; ACC[1][1]+=AV.y*BV.y; ACC[1][2]+=AV.y*BV.z; ACC[1][3]+=AV.y*BV.w; \
  ACC[2][0]+=AV.z*BV.x; ACC[2][1]+=AV.z*BV.y; ACC[2][2]+=AV.z*BV.z; ACC[2][3]+=AV.z*BV.w; \
  ACC[3][0]+=AV.w*BV.x; ACC[3][1]+=AV.w*BV.y; ACC[3][2]+=AV.w*BV.z; ACC[3][3]+=AV.w*BV.w; \
}while(0)

__device__ __forceinline__ void gemm_nn_tile(
    const float* __restrict__ A, int lda,
    const float* __restrict__ B, int ldb,
    const float* __restrict__ lsc,
    int K, int m0, int n0, float acc[4][4],
    float (&As)[16][68], float (&Bs)[16][68])
{
  const int tid = threadIdx.x;
  const int ar = tid >> 2, ac = (tid & 3) << 2;
  const int br = tid >> 4, bc = (tid & 15) << 2;
  const int my = tid & 15, nx = tid >> 4;
  for (int k0 = 0; k0 < K; k0 += 16) {
    float4 av = *(const float4*)&A[(size_t)(m0 + ar) * lda + k0 + ac];
    float4 bv = *(const float4*)&B[(size_t)(k0 + br) * ldb + n0 + bc];
    if (lsc) { float s = lsc[k0 + br]; bv.x*=s; bv.y*=s; bv.z*=s; bv.w*=s; }
    __syncthreads();
    As[ac+0][ar]=av.x; As[ac+1][ar]=av.y; As[ac+2][ar]=av.z; As[ac+3][ar]=av.w;
    *(float4*)&Bs[br][bc] = bv;
    __syncthreads();
    #pragma unroll
    for (int kk = 0; kk < 16; ++kk) {
      float4 a = *(const float4*)&As[kk][my*4];
      float4 b = *(const float4*)&Bs[kk][nx*4];
      FMA44(acc,a,b);
    }
  }
}

__global__ __launch_bounds__(256) void fwd_kernel(
    const float* __restrict__ w0c, const float* __restrict__ w2c,
    const float* __restrict__ q, const float* __restrict__ kin,
    float* __restrict__ sq, float* __restrict__ gba,
    float* __restrict__ hbmp, float* __restrict__ hid,
    int c, int nsrc)
{
  __shared__ float As0[16][68], As1[16][68], Bs[16][68];
  const int b = blockIdx.x;
  const int nt = b & 3, mt = (b >> 2) & 7;
  const int src = (b >> 5) % nsrc;
  const int bh = b / (32 * nsrc);
  const int m0 = mt * 64, n0 = nt * 64;
  const float* A0 = w0c + (size_t)bh * DI_ * DD;
  const float* A1 = w2c + (size_t)bh * DI_ * DD;
  const float* S  = (src == 0 ? q : kin) + ((size_t)bh * SEQT + (size_t)c * CS_) * DD;
  float acc0[4][4] = {}, acc1[4][4] = {};
  const int tid = threadIdx.x;
  const int r = tid >> 2, c4 = (tid & 3) << 2;
  const int my = tid & 15, nx = tid >> 4;
  for (int k0 = 0; k0 < DD; k0 += 16) {
    float4 a0 = *(const float4*)&A0[(size_t)(m0 + r) * DD + k0 + c4];
    float4 a1 = *(const float4*)&A1[(size_t)(m0 + r) * DD + k0 + c4];
    float4 bv = *(const float4*)&S [(size_t)(n0 + r) * DD + k0 + c4];
    __syncthreads();
    As0[c4+0][r]=a0.x; As0[c4+1][r]=a0.y; As0[c4+2][r]=a0.z; As0[c4+3][r]=a0.w;
    As1[c4+0][r]=a1.x; As1[c4+1][r]=a1.y; As1[c4+2][r]=a1.z; As1[c4+3][r]=a1.w;
    Bs [c4+0][r]=bv.x; Bs [c4+1][r]=bv.y; Bs [c4+2][r]=bv.z; Bs [c4+3][r]=bv.w;
    __syncthreads();
    #pragma unroll
    for (int kk = 0; kk < 16; ++kk) {
      float4 a  = *(const float4*)&As0[kk][my*4];
      float4 a2 = *(const float4*)&As1[kk][my*4];
      float4 bb = *(const float4*)&Bs [kk][nx*4];
      FMA44(acc0,a,bb);
      FMA44(acc1,a2,bb);
    }
  }
  #pragma unroll
  for (int um = 0; um < 4; ++um) {
    int j = m0 + my*4 + um;
    size_t base = ((size_t)bh * DI_ + j) * CS_ + n0 + nx*4;
    if (src == 0) {
      float4 o;
      o.x = acc0[um][0]*sigm(acc0[um][0])*acc1[um][0];
      o.y = acc0[um][1]*sigm(acc0[um][1])*acc1[um][1];
      o.z = acc0[um][2]*sigm(acc0[um][2])*acc1[um][2];
      o.w = acc0[um][3]*sigm(acc0[um][3])*acc1[um][3];
      *(float4*)&sq[base] = o;
    } else {
      float4 g = make_float4(acc0[um][0],acc0[um][1],acc0[um][2],acc0[um][3]);
      float4 h = make_float4(acc1[um][0],acc1[um][1],acc1[um][2],acc1[um][3]);
      float4 hd;
      hd.x = g.x*sigm(g.x)*h.x; hd.y = g.y*sigm(g.y)*h.y;
      hd.z = g.z*sigm(g.z)*h.z; hd.w = g.w*sigm(g.w)*h.w;
      *(float4*)&gba[base]  = g;
      *(float4*)&hbmp[base] = h;
      *(float4*)&hid[base]  = hd;
    }
  }
}

__global__ __launch_bounds__(256) void out_kernel(
    const float* __restrict__ w1c, const float* __restrict__ sq,
    float* __restrict__ out, int c)
{
  __shared__ float As[16][68], Bs[16][68];
  const int b = blockIdx.x;
  const int nt = b & 3, mt = (b >> 2) & 7, bh = b >> 5;
  const int m0 = mt * 64, n0 = nt * 64;
  float acc[4][4] = {};
  gemm_nn_tile(w1c + (size_t)bh*DD*DI_, DI_, sq + (size_t)bh*DI_*CS_, CS_,
               nullptr, DI_, m0, n0, acc, As, Bs);
  const int my = threadIdx.x & 15, nx = threadIdx.x >> 4;
  #pragma unroll
  for (int un = 0; un < 4; ++un) {
    int t = n0 + nx*4 + un;
    float4 o = make_float4(acc[0][un],acc[1][un],acc[2][un],acc[3][un]);
    *(float4*)&out[((size_t)bh*SEQT + (size_t)c*CS_ + t)*DD + m0 + my*4] = o;
  }
}

__global__ __launch_bounds__(256) void dh_kernel(
    const float* __restrict__ vin, const float* __restrict__ w1c,
    const float* __restrict__ gba, const float* __restrict__ hbmp,
    float* __restrict__ dgb, float* __restrict__ dhb, int c)
{
  __shared__ float As[16][68], Bs[16][68];
  const int b = blockIdx.x;
  const int nt = b & 7, mt = (b >> 3) & 3, bh = b >> 5;
  const int m0 = mt * 64, n0 = nt * 64;
  float acc[4][4] = {};
  gemm_nn_tile(vin + ((size_t)bh*SEQT + (size_t)c*CS_)*DD, DD,
               w1c + (size_t)bh*DD*DI_, DI_, nullptr, DD, m0, n0, acc, As, Bs);
  const int my = threadIdx.x & 15, nx = threadIdx.x >> 4;
  #pragma unroll
  for (int un = 0; un < 4; ++un) {
    int j = n0 + nx*4 + un;
    size_t idx = ((size_t)bh*DI_ + j)*CS_ + m0 + my*4;
    float4 g4 = *(const float4*)&gba[idx];
    float4 h4 = *(const float4*)&hbmp[idx];
    float ge[4] = {g4.x,g4.y,g4.z,g4.w};
    float hb[4] = {h4.x,h4.y,h4.z,h4.w};
    float dg[4], dh[4];
    #pragma unroll
    for (int u = 0; u < 4; ++u) {
      float e = acc[u][un];
      float s = sigm(ge[u]);
      dh[u] = e * ge[u] * s;
      float dgate = e * hb[u];
      dg[u] = dgate * s * (1.f + ge[u]*(1.f - s));
    }
    *(float4*)&dgb[idx] = make_float4(dg[0],dg[1],dg[2],dg[3]);
    *(float4*)&dhb[idx] = make_float4(dh[0],dh[1],dh[2],dh[3]);
  }
}

__global__ __launch_bounds__(256) void dw_kernel(
    const float* __restrict__ dgb, const float* __restrict__ dhb,
    const float* __restrict__ hid, const float* __restrict__ kin,
    const float* __restrict__ vin,
    const float* __restrict__ lr0, const float* __restrict__ lr1,
    const float* __restrict__ lr2,
    float* __restrict__ dm, float* __restrict__ X,
    const float* __restrict__ mi, float* __restrict__ fro, int c)
{
  __shared__ float As[16][68], Bs[16][68];
  __shared__ float red[4];
  const int b = blockIdx.x;
  const int nt = b & 7, mt = (b >> 3) & 7, bh = (b >> 6) & 7, w = b >> 9;
  const int m0 = mt * 64, n0 = nt * 64;
  const float* Aop = (w==0 ? dgb : (w==1 ? hid : dhb)) + (size_t)bh*DI_*CS_;
  const float* Bop = (w==1 ? vin : kin) + ((size_t)bh*SEQT + (size_t)c*CS_)*DD;
  const float* l   = (w==0 ? lr0 : (w==1 ? lr1 : lr2)) + (size_t)bh*SEQT + (size_t)c*CS_;
  float acc[4][4] = {};
  gemm_nn_tile(Aop, CS_, Bop, DD, l, CS_, m0, n0, acc, As, Bs);
  const int my = threadIdx.x & 15, nx = threadIdx.x >> 4;
  const float m_i = mi[bh*NUP + c];
  const int mat = bh*3 + w;
  const size_t base = (size_t)mat * DI_ * DD;
  float fs = 0.f;
  #pragma unroll
  for (int um = 0; um < 4; ++um) {
    size_t idx = base + (size_t)(m0 + my*4 + um)*DD + n0 + nx*4;
    float4 dmv = *(const float4*)&dm[idx];
    float4 dv;
    dv.x = acc[um][0] + dmv.x*m_i; dv.y = acc[um][1] + dmv.y*m_i;
    dv.z = acc[um][2] + dmv.z*m_i; dv.w = acc[um][3] + dmv.w*m_i;
    *(float4*)&dm[idx] = dv;
    *(float4*)&X[idx]  = dv;
    fs += dv.x*dv.x + dv.y*dv.y + dv.z*dv.z + dv.w*dv.w;
  }
  #pragma unroll
  for (int off = 32; off > 0; off >>= 1) fs += __shfl_down(fs, off, 64);
  const int wid = threadIdx.x >> 6;
  if ((threadIdx.x & 63) == 0) red[wid] = fs;
  __syncthreads();
  if (threadIdx.x == 0) atomicAdd(&fro[mat], red[0]+red[1]+red[2]+red[3]);
}

__global__ __launch_bounds__(256) void ns_scale_kernel(float* __restrict__ X,
                                                       const float* __restrict__ fro)
{
  int gid = blockIdx.x*256 + threadIdx.x;
  int mat = gid >> 16;
  float inv = 1.0f/(sqrtf(fro[mat]) + 1e-7f);
  float4* p = ((float4*)X) + gid;
  float4 v = *p; v.x*=inv; v.y*=inv; v.z*=inv; v.w*=inv; *p = v;
}

__global__ __launch_bounds__(256) void nsA_kernel(const float* __restrict__ X,
                                                  float* __restrict__ Ab)
{
  __shared__ float As[16][68], Bs[16][68];
  const int b = blockIdx.x;
  const int nt = b & 7, mt = (b >> 3) & 7, mat = b >> 6;
  const int m0 = mt*64, n0 = nt*64;
  const float* Xm = X + (size_t)mat * DI_ * DD;
  float acc[4][4] = {};
  const int tid = threadIdx.x;
  const int r = tid >> 2, c4 = (tid & 3) << 2;
  const int my = tid & 15, nx = tid >> 4;
  for (int k0 = 0; k0 < DD; k0 += 16) {
    float4 av = *(const float4*)&Xm[(size_t)(m0 + r)*DD + k0 + c4];
    float4 bv = *(const float4*)&Xm[(size_t)(n0 + r)*DD + k0 + c4];
    __syncthreads();
    As[c4+0][r]=av.x; As[c4+1][r]=av.y; As[c4+2][r]=av.z; As[c4+3][r]=av.w;
    Bs[c4+0][r]=bv.x; Bs[c4+1][r]=bv.y; Bs[c4+2][r]=bv.z; Bs[c4+3][r]=bv.w;
    __syncthreads();
    #pragma unroll
    for (int kk = 0; kk < 16; ++kk) {
      float4 a = *(const float4*)&As[kk][my*4];
      float4 bb = *(const float4*)&Bs[kk][nx*4];
      FMA44(acc,a,bb);
    }
  }
  #pragma unroll
  for (int um = 0; um < 4; ++um) {
    size_t idx = (size_t)mat*DI_*DD + (size_t)(m0 + my*4 + um)*DD + n0 + nx*4;
    *(float4*)&Ab[idx] = make_float4(acc[um][0],acc[um][1],acc[um][2],acc[um][3]);
  }
}

__global__ __launch_bounds__(256) void nsY_kernel(const float* __restrict__ Ab,
                                                  const float* __restrict__ X,
                                                  float* __restrict__ Y)
{
  __shared__ float As[16][68], Bs[16][68];
  const int b = blockIdx.x;
  const int nt = b & 7, mt = (b >> 3) & 7, mat = b >> 6;
  const int m0 = mt*64, n0 = nt*64;
  float acc[4][4] = {};
  gemm_nn_tile(Ab + (size_t)mat*DI_*DD, DD, X + (size_t)mat*DI_*DD, DD,
               nullptr, DD, m0, n0, acc, As, Bs);
  const int my = threadIdx.x & 15, nx = threadIdx.x >> 4;
  #pragma unroll
  for (int um = 0; um < 4; ++um) {
    size_t idx = (size_t)mat*DI_*DD + (size_t)(m0 + my*4 + um)*DD + n0 + nx*4;
    *(float4*)&Y[idx] = make_float4(acc[um][0],acc[um][1],acc[um][2],acc[um][3]);
  }
}

__global__ __launch_bounds__(256) void nsZ_kernel(const float* __restrict__ Ab,
                                                  const float* __restrict__ Y,
                                                  float* __restrict__ X,
                                                  float ca, float cb, float cg)
{
  __shared__ float As[16][68], Bs[16][68];
  const int b = blockIdx.x;
  const int nt = b & 7, mt = (b >> 3) & 7, mat = b >> 6;
  const int m0 = mt*64, n0 = nt*64;
  float acc[4][4] = {};
  gemm_nn_tile(Ab + (size_t)mat*DI_*DD, DD, Y + (size_t)mat*DI_*DD, DD,
               nullptr, DD, m0, n0, acc, As, Bs);
  const int my = threadIdx.x & 15, nx = threadIdx.x >> 4;
  #pragma unroll
  for (int um = 0; um < 4; ++um) {
    size_t idx = (size_t)mat*DI_*DD + (size_t)(m0 + my*4 + um)*DD + n0 + nx*4;
    float4 xv = *(const float4*)&X[idx];
    float4 yv = *(const float4*)&Y[idx];
    float4 ov;
    ov.x = ca*xv.x + cb*yv.x + cg*acc[um][0];
    ov.y = ca*xv.y + cb*yv.y + cg*acc[um][1];
    ov.z = ca*xv.z + cb*yv.z + cg*acc[um][2];
    ov.w = ca*xv.w + cb*yv.w + cg*acc[um][3];
    *(float4*)&X[idx] = ov;
  }
}

__global__ __launch_bounds__(256) void update_kernel(
    const float* __restrict__ X, const float* __restrict__ XT,
    float* __restrict__ wm, float* __restrict__ wc,
    const float* __restrict__ wn, const float* __restrict__ mli, int c)
{
  const int gr = blockIdx.x*4 + (threadIdx.x >> 6);
  const int lane = threadIdx.x & 63;
  const int mat = gr >> 9, i = gr & 511;
  const int bh = mat / 3, w = mat - bh*3;
  const float* xrow = (w == 1) ? (XT + ((size_t)bh*512 + i)*512)
                               : (X  + (size_t)mat*DI_*DD + (size_t)i*512);
  float* wmrow = wm + ((size_t)w*BH + bh)*DI_*DD + (size_t)i*512;
  float* wcrow = wc + ((size_t)w*BH + bh)*DI_*DD + (size_t)i*512;
  const float ml = mli[bh*NUP + c];
  float vreg[8];
  float ss = 0.f;
  #pragma unroll
  for (int u = 0; u < 8; ++u) {
    int col = lane + 64*u;
    float nv = wmrow[col] + xrow[col]*ml;
    vreg[u] = nv; ss += nv*nv;
    wmrow[col] = nv;
  }
  #pragma unroll
  for (int off = 32; off > 0; off >>= 1) ss += __shfl_xor(ss, off, 64);
  const float scale = wn[w*4096 + bh*512 + i] / (sqrtf(ss) + 1e-5f);
  #pragma unroll
  for (int u = 0; u < 8; ++u) wcrow[lane + 64*u] = vreg[u]*scale;
}

// ================================ LAUNCHERS =================================

static void launch_fallback(void* const* d_in, void* d_out, void* d_ws, hipStream_t stream)
{
  const float* w0  = (const float*)d_in[0];
  const float* w1  = (const float*)d_in[1];
  const float* w2  = (const float*)d_in[2];
  const float* q   = (const float*)d_in[3];
  const float* k   = (const float*)d_in[4];
  const float* v   = (const float*)d_in[5];
  const float* lr0 = (const float*)d_in[6];
  const float* lr1 = (const float*)d_in[7];
  const float* lr2 = (const float*)d_in[8];
  const float* mom = (const float*)d_in[9];
  const float* mlr = (const float*)d_in[10];
  float* out = (float*)d_out;
  float* ws  = (float*)d_ws;

  float* WM  = ws + OFF_WM;  float* WC  = ws + OFF_WC;  float* DM  = ws + OFF_DM;
  float* X   = ws + OFF_X;   float* A   = ws + OFF_A;   float* SQ  = ws + OFF_SQ;
  float* GBA = ws + OFF_GBA; float* HBMb= ws + OFF_HBM; float* HID = ws + OFF_HID;
  float* DGB = ws + OFF_DGB; float* DHB = ws + OFF_DHB; float* Y   = ws + OFF_Y;
  float* FRO = ws + OFF_FRO; float* MI  = ws + OFF_MI;  float* MLI = ws + OFF_MLI;
  float* WN  = ws + OFF_WN;

  for (int w = 0; w < 3; ++w) {
    const float* src = (w==0 ? w0 : (w==1 ? w1 : w2));
    hipMemcpyAsync(WM + (size_t)w*SZ_W1, src, SZ_W1*sizeof(float),
                   hipMemcpyDeviceToDevice, stream);
    hipMemcpyAsync(WC + (size_t)w*SZ_W1, src, SZ_W1*sizeof(float),
                   hipMemcpyDeviceToDevice, stream);
  }
  hipMemsetAsync(DM, 0, SZ_W*sizeof(float), stream);
  hipMemsetAsync(FRO, 0, 360*sizeof(float), stream);
  wnorm_kernel<<<3072, 256, 0, stream>>>(w0, w1, w2, WN);
  scalars_kernel<<<BH*NUP, 64, 0, stream>>>(mom, mlr, MI, MLI);

  for (int c = 0; c < NUP; ++c) {
    fwd_kernel<<<512, 256, 0, stream>>>(WC, WC + 2*SZ_W1, q, k, SQ, GBA, HBMb, HID, c, 2);
    out_kernel<<<256, 256, 0, stream>>>(WC + SZ_W1, SQ, out, c);
    dh_kernel<<<256, 256, 0, stream>>>(v, WC + SZ_W1, GBA, HBMb, DGB, DHB, c);
    dw_kernel<<<1536, 256, 0, stream>>>(DGB, DHB, HID, k, v, lr0, lr1, lr2,
                                        DM, X, MI, FRO + c*24, c);
    ns_scale_kernel<<<6144, 256, 0, stream>>>(X, FRO + c*24);
    for (int s = 0; s < 5; ++s) {
      nsA_kernel<<<1536, 256, 0, stream>>>(X, A);
      nsY_kernel<<<1536, 256, 0, stream>>>(A, X, Y);
      nsZ_kernel<<<1536, 256, 0, stream>>>(A, Y, X, NSC[s][0], NSC[s][1], NSC[s][2]);
    }
    transpose_x1<<<512, 256, 0, stream>>>(X, Y);
    update_kernel<<<3072, 256, 0, stream>>>(X, Y, WM, WC, WN, MLI, c);
  }
  fwd_kernel<<<256, 256, 0, stream>>>(WC, WC + 2*SZ_W1, q, k, SQ, GBA, HBMb, HID, NUP, 1);
  out_kernel<<<256, 256, 0, stream>>>(WC + SZ_W1, SQ, out, NUP);
}

static void launch_primary(void* const* d_in, void* d_out, void* d_ws, hipStream_t stream)
{
  const float* w0  = (const float*)d_in[0];
  const float* w1  = (const float*)d_in[1];
  const float* w2  = (const float*)d_in[2];
  const float* q   = (const float*)d_in[3];
  const float* kk  = (const float*)d_in[4];
  const float* v   = (const float*)d_in[5];
  const float* lr0 = (const float*)d_in[6];
  const float* lr1 = (const float*)d_in[7];
  const float* lr2 = (const float*)d_in[8];
  const float* mom = (const float*)d_in[9];
  const float* mlr = (const float*)d_in[10];
  float* out = (float*)d_out;
  char* base = (char*)d_ws;

  float* WM   = (float*)(base + 0);
  float* DM   = (float*)(base + 25165824);
  float* Xf   = (float*)(base + 50331648);
  u16* WCH    = (u16*)(base + 75497472);
  u16* WCL    = (u16*)(base + 88080384);
  char* OVER  = base + 100663296;
  float* FRO  = (float*)(base + 176160768);
  float* MI   = (float*)(base + 176162208);
  float* MLI  = (float*)(base + 176162688);
  float* WN   = (float*)(base + 176163168);

  u16* S1H = (u16*)(OVER);             u16* S1L = (u16*)(OVER + 12582912);
  u16* S2H = (u16*)(OVER + 25165824);  u16* S2L = (u16*)(OVER + 37748736);
  u16* S3H = (u16*)(OVER + 50331648);  u16* S3L = (u16*)(OVER + 62914560);

  float* P0q  = (float*)(OVER + 0);
  float* P2q  = (float*)(OVER + 4194304);
  float* GBA  = (float*)(OVER + 8388608);
  float* HBMa = (float*)(OVER + 12582912);
  float* HID  = (float*)(OVER + 16777216);
  float* DGB  = (float*)(OVER + 20971520);
  float* DHB  = (float*)(OVER + 25165824);
  u16* QcH = (u16*)(OVER + 29360128);  u16* QcL = (u16*)(OVER + 31457280);
  u16* KcH = (u16*)(OVER + 33554432);  u16* KcL = (u16*)(OVER + 35651584);
  u16* VcH = (u16*)(OVER + 37748736);  u16* VcL = (u16*)(OVER + 39845888);
  u16* KTH = (u16*)(OVER + 41943040);  u16* KTL = (u16*)(OVER + 44040192);
  u16* VTH = (u16*)(OVER + 46137344);  u16* VTL = (u16*)(OVER + 48234496);
  u16* SQH = (u16*)(OVER + 50331648);  u16* SQL = (u16*)(OVER + 52428800);
  u16* DGBTH = (u16*)(OVER + 54525952); u16* DGBTL = (u16*)(OVER + 56623104);
  u16* DHBTH = (u16*)(OVER + 58720256); u16* DHBTL = (u16*)(OVER + 60817408);
  u16* HIDTH = (u16*)(OVER + 62914560); u16* HIDTL = (u16*)(OVER + 65011712);
  u16* W1TH = (u16*)(OVER + 67108864); u16* W1TL = (u16*)(OVER + 71303168);
  float* XT1 = (float*)(OVER + 50331648);  // update-time scratch (S3 region)

  for (int w = 0; w < 3; ++w) {
    const float* src = (w==0 ? w0 : (w==1 ? w1 : w2));
    hipMemcpyAsync(WM + (size_t)w*2097152, src, 2097152*sizeof(float),
                   hipMemcpyDeviceToDevice, stream);
  }
  hipMemsetAsync(DM, 0, 25165824, stream);
  hipMemsetAsync(FRO, 0, 360*sizeof(float), stream);
  k_cvt_w<<<3072, 256, 0, stream>>>(w0, w1, w2, WCH, WCL);
  wnorm_kernel<<<3072, 256, 0, stream>>>(w0, w1, w2, WN);
  scalars_kernel<<<BH*NUP, 64, 0, stream>>>(mom, mlr, MI, MLI);

  for (int c = 0; c < NUP; ++c) {
    k_cvt_qkv<<<1536, 256, 0, stream>>>(q, kk, v, QcH, QcL, KcH, KcL, VcH, VcL, c);
    k_tb<<<512, 256, 0, stream>>>(WCH, WCL, W1TH, W1TL);
    k_fwd<<<256, 256, 0, stream>>>(QcH, QcL, KcH, KcL, WCH, WCL, P0q, P2q, GBA, HBMa);
    k_combine<<<2048, 256, 0, stream>>>(P0q, P2q, GBA, HBMa, SQH, SQL, HID);
    k_outdh<<<128, 256, 0, stream>>>(SQH, SQL, WCH, WCL, VcH, VcL, W1TH, W1TL,
                                     GBA, HBMa, DGB, DHB, out, c);
    k_tc<<<1280, 256, 0, stream>>>(DGB, DHB, HID, kk, v, lr0, lr1, lr2,
                                   DGBTH, DGBTL, DHBTH, DHBTL, HIDTH, HIDTL,
                                   KTH, KTL, VTH, VTL, c);
    k_dw<<<384, 256, 0, stream>>>(DGBTH, DGBTL, DHBTH, DHBTL, HIDTH, HIDTL,
                                  KTH, KTL, VTH, VTL, DM, Xf, MI, FRO + c*24, c);
    k_scale<<<6144, 256, 0, stream>>>(Xf, S1H, S1L, FRO + c*24);
    for (int s = 0; s < 5; ++s) {
      u16* xsH = (s & 1) ? S2H : S1H;  u16* xsL = (s & 1) ? S2L : S1L;
      u16* asH = (s & 1) ? S1H : S2H;  u16* asL = (s & 1) ? S1L : S2L;
      k_nsA<<<384, 256, 0, stream>>>(xsH, xsL, asH, asL);
      k_nsB<<<384, 256, 0, stream>>>(asH, asL, S3H, S3L, NSC[s][1], NSC[s][2]);
      k_nsZ<<<384, 256, 0, stream>>>(S3H, S3L, xsH, xsL, Xf, asH, asL, NSC[s][0]);
    }
    transpose_x1<<<512, 256, 0, stream>>>(Xf, XT1);
    k_update2<<<3072, 256, 0, stream>>>(Xf, XT1, WM, WCH, WCL, WN, MLI, c);
  }
  // final forward-only chunk
  k_cvt_qkv<<<1536, 256, 0, stream>>>(q, kk, v, QcH, QcL, KcH, KcL, VcH, VcL, NUP);
  k_fwd<<<128, 256, 0, stream>>>(QcH, QcL, KcH, KcL, WCH, WCL, P0q, P2q, GBA, HBMa);
  k_combine<<<1024, 256, 0, stream>>>(P0q, P2q, GBA, HBMa, SQH, SQL, HID);
  k_outdh<<<64, 256, 0, stream>>>(SQH, SQL, WCH, WCL, VcH, VcL, W1TH, W1TL,
                                  GBA, HBMa, DGB, DHB, out, NUP);
}

extern "C" void kernel_launch(void* const* d_in, const int* in_sizes, int n_in,
                              void* d_out, int out_size, void* d_ws, size_t ws_size,
                              hipStream_t stream)
{
  (void)in_sizes; (void)n_in; (void)out_size;
  if (ws_size >= 176212320ull) {
    launch_primary(d_in, d_out, d_ws, stream);
  } else {
    launch_fallback(d_in, d_out, d_ws, stream);
  }
}

// Round 3
// 12666.518 us; speedup vs baseline: 1.8681x; 1.2676x over previous
//
#include <hip/hip_runtime.h>
#include <math.h>

#define BH   8
#define SEQT 4096
#define DD   512
#define DI_  512
#define CS_  256
#define NUP  15

typedef unsigned short u16;
typedef float f32x16 __attribute__((ext_vector_type(16)));
typedef short v8s    __attribute__((ext_vector_type(8)));
typedef _Float16 v8h __attribute__((ext_vector_type(8)));

__device__ __forceinline__ float sigm(float x){ return 1.0f/(1.0f+expf(-x)); }

__device__ __forceinline__ float bf2f(u16 h){
  union{unsigned u; float f;} v; v.u = ((unsigned)h)<<16; return v.f;
}
__device__ __forceinline__ u16 f2bf_rn(float x){
  union{float f; unsigned u;} v; v.f = x;
  unsigned r = (v.u + 0x7fffu + ((v.u>>16)&1u)) >> 16;
  return (u16)r;
}
__device__ __forceinline__ void split_bf(float x, u16 &h, u16 &l){
  h = f2bf_rn(x);
  l = f2bf_rn(x - bf2f(h));
}
__device__ __forceinline__ float h2f(u16 u){
  union{ _Float16 h; u16 u;} v; v.u = u; return (float)v.h;
}
__device__ __forceinline__ void split_h(float x, u16 &h, u16 &l){
  _Float16 hh = (_Float16)x;
  float hf = (float)hh;
  _Float16 ll = (_Float16)(x - hf);
  union{ _Float16 h; u16 u;} a, b; a.h = hh; b.h = ll;
  h = a.u; l = b.u;
}

// ============================ PRIMARY (MFMA) PATH ============================
// All GEMMs NT: C[m][n] = sum_k A[m][k]*B[n][k].
// MODE 0: bf16 split 3-product (hh + hl + lh), arrays Ah,Al,Bh,Bl.
// MODE 1: f16 2-product, B-side corrected: P = Ah.(Bh+Bl). Arrays Ah,Bh,Bl.
// 128x128 block tile, 4 waves (2x2), wave = 2x2 frags of 32x32x16.
// K-loop software-pipelined: next iteration's global loads issued before the
// barriers of the current iteration (hides L2/HBM latency behind MFMA).

struct Smem {
  u16 Ah[128][40]; u16 Al[128][40];
  u16 Bh[128][40]; u16 Bl[128][40];
};

#define TIDS \
  const int tid = threadIdx.x; const int lane = tid & 63; \
  const int wv = tid >> 6, wm = wv & 1, wn = wv >> 1; \
  const int l31 = lane & 31, hv = lane >> 5;

template<int MODE>
__device__ __forceinline__ void mm_core(
    const u16* __restrict__ Ah, const u16* __restrict__ Al, int lda, int m0,
    const u16* __restrict__ Bh, const u16* __restrict__ Bl, int ldb, int n0,
    int K, Smem& sm, f32x16 (&acc)[2][2])
{
  TIDS;
  const int sr = tid >> 1, sc = (tid & 1) << 4;
  const u16* pAh = Ah + (size_t)(m0 + sr) * lda + sc;
  const u16* pAl = (MODE==0) ? (Al + (size_t)(m0 + sr) * lda + sc) : pAh;
  const u16* pBh = Bh + (size_t)(n0 + sr) * ldb + sc;
  const u16* pBl = Bl + (size_t)(n0 + sr) * ldb + sc;
  int4 a0,a1,a2,a3,b0,b1,b2,b3;
  a0 = *(const int4*)(pAh); a1 = *(const int4*)(pAh + 8);
  if (MODE==0){ a2 = *(const int4*)(pAl); a3 = *(const int4*)(pAl + 8); }
  b0 = *(const int4*)(pBh); b1 = *(const int4*)(pBh + 8);
  b2 = *(const int4*)(pBl); b3 = *(const int4*)(pBl + 8);
  for (int kb = 0; kb < K; kb += 32) {
    int4 na0,na1,na2,na3,nb0,nb1,nb2,nb3;
    const int kn = kb + 32;
    if (kn < K) {
      na0 = *(const int4*)(pAh + kn); na1 = *(const int4*)(pAh + kn + 8);
      if (MODE==0){ na2 = *(const int4*)(pAl + kn); na3 = *(const int4*)(pAl + kn + 8); }
      nb0 = *(const int4*)(pBh + kn); nb1 = *(const int4*)(pBh + kn + 8);
      nb2 = *(const int4*)(pBl + kn); nb3 = *(const int4*)(pBl + kn + 8);
    }
    __syncthreads();
    *(int4*)&sm.Ah[sr][sc] = a0; *(int4*)&sm.Ah[sr][sc+8] = a1;
    if (MODE==0){ *(int4*)&sm.Al[sr][sc] = a2; *(int4*)&sm.Al[sr][sc+8] = a3; }
    *(int4*)&sm.Bh[sr][sc] = b0; *(int4*)&sm.Bh[sr][sc+8] = b1;
    *(int4*)&sm.Bl[sr][sc] = b2; *(int4*)&sm.Bl[sr][sc+8] = b3;
    __syncthreads();
    #pragma unroll
    for (int h = 0; h < 2; ++h) {
      const int col = h*16 + hv*8;
      if (MODE==0) {
        v8s afh[2], afl[2], bfh[2], bfl[2];
        #pragma unroll
        for (int i = 0; i < 2; ++i) {
          afh[i] = *(const v8s*)&sm.Ah[wm*64 + i*32 + l31][col];
          afl[i] = *(const v8s*)&sm.Al[wm*64 + i*32 + l31][col];
          bfh[i] = *(const v8s*)&sm.Bh[wn*64 + i*32 + l31][col];
          bfl[i] = *(const v8s*)&sm.Bl[wn*64 + i*32 + l31][col];
        }
        #pragma unroll
        for (int i = 0; i < 2; ++i)
          #pragma unroll
          for (int j = 0; j < 2; ++j) {
            acc[i][j] = __builtin_amdgcn_mfma_f32_32x32x16_bf16(afh[i], bfh[j], acc[i][j], 0, 0, 0);
            acc[i][j] = __builtin_amdgcn_mfma_f32_32x32x16_bf16(afh[i], bfl[j], acc[i][j], 0, 0, 0);
            acc[i][j] = __builtin_amdgcn_mfma_f32_32x32x16_bf16(afl[i], bfh[j], acc[i][j], 0, 0, 0);
          }
      } else {
        v8h afh[2], bfh[2], bfl[2];
        #pragma unroll
        for (int i = 0; i < 2; ++i) {
          afh[i] = *(const v8h*)&sm.Ah[wm*64 + i*32 + l31][col];
          bfh[i] = *(const v8h*)&sm.Bh[wn*64 + i*32 + l31][col];
          bfl[i] = *(const v8h*)&sm.Bl[wn*64 + i*32 + l31][col];
        }
        #pragma unroll
        for (int i = 0; i < 2; ++i)
          #pragma unroll
          for (int j = 0; j < 2; ++j) {
            acc[i][j] = __builtin_amdgcn_mfma_f32_32x32x16_f16(afh[i], bfh[j], acc[i][j], 0, 0, 0);
            acc[i][j] = __builtin_amdgcn_mfma_f32_32x32x16_f16(afh[i], bfl[j], acc[i][j], 0, 0, 0);
          }
      }
    }
    if (kn < K) {
      a0=na0; a1=na1; b0=nb0; b1=nb1; b2=nb2; b3=nb3;
      if (MODE==0){ a2=na2; a3=na3; }
    }
  }
}

#define EPI_BEGIN \
  _Pragma("unroll") for (int i = 0; i < 2; ++i) { \
  _Pragma("unroll") for (int j = 0; j < 2; ++j) { \
  _Pragma("unroll") for (int rg = 0; rg < 16; ++rg) { \
    const int gr = m0 + wm*64 + i*32 + (rg&3) + 8*(rg>>2) + 4*hv; \
    const int gc = n0 + wn*64 + j*32 + l31; \
    const float av = acc[i][j][rg];
#define EPI_END }}}

// ---- fwd: P[t][j] = chunk[t][d] . W[j][d] ; 4 combos (q/k x w0/w2) ----
__global__ __launch_bounds__(256) void k_fwd(
    const u16* QcH, const u16* QcL, const u16* KcH, const u16* KcL,
    const u16* WCH, const u16* WCL,
    float* P0q, float* P2q, float* GBA, float* HBMa)
{
  __shared__ Smem sm;
  const int bx = blockIdx.x;
  const int nt = bx & 3, mt = (bx >> 2) & 1, bh = (bx >> 3) & 7, combo = bx >> 6;
  const int m0 = mt*128, n0 = nt*128;
  const u16* Ah = (combo < 2 ? QcH : KcH) + (size_t)bh*131072;
  const u16* Al = (combo < 2 ? QcL : KcL) + (size_t)bh*131072;
  const int w = (combo & 1) ? 2 : 0;
  const u16* Bh = WCH + ((size_t)(w*8 + bh))*262144;
  const u16* Bl = WCL + ((size_t)(w*8 + bh))*262144;
  float* dst = (combo==0 ? P0q : combo==1 ? P2q : combo==2 ? GBA : HBMa) + (size_t)bh*131072;
  f32x16 acc[2][2] = {};
  mm_core<0>(Ah, Al, 512, m0, Bh, Bl, 512, n0, 512, sm, acc);
  TIDS;
  EPI_BEGIN
    dst[(size_t)gr*512 + gc] = av;
  EPI_END
}

// ---- out (flag0): O[t][d] = SQ[t][j].W1[d][j] ; dh (flag1): E[t][j]=V[t][d].W1T[j][d] ----
__global__ __launch_bounds__(256) void k_outdh(
    const u16* SQH, const u16* SQL, const u16* WCH, const u16* WCL,
    const u16* VcH, const u16* VcL, const u16* W1TH, const u16* W1TL,
    const float* GBA, const float* HBMa, float* DGB, float* DHB,
    float* out, int c)
{
  __shared__ Smem sm;
  const int bx = blockIdx.x;
  const int flag = bx >> 6;
  const int r = bx & 63;
  const int nt = r & 3, mt = (r >> 2) & 1, bh = r >> 3;
  const int m0 = mt*128, n0 = nt*128;
  f32x16 acc[2][2] = {};
  TIDS;
  if (flag == 0) {
    mm_core<0>(SQH + (size_t)bh*131072, SQL + (size_t)bh*131072, 512, m0,
            WCH + ((size_t)(8 + bh))*262144, WCL + ((size_t)(8 + bh))*262144, 512, n0,
            512, sm, acc);
    float* o = out + ((size_t)bh*SEQT + (size_t)c*CS_) * DD;
    EPI_BEGIN
      o[(size_t)gr*512 + gc] = av;
    EPI_END
  } else {
    mm_core<0>(VcH + (size_t)bh*131072, VcL + (size_t)bh*131072, 512, m0,
            W1TH + (size_t)bh*262144, W1TL + (size_t)bh*262144, 512, n0,
            512, sm, acc);
    EPI_BEGIN
      size_t gi = (size_t)bh*131072 + (size_t)gr*512 + gc;
      float g = GBA[gi], hb = HBMa[gi];
      float s = sigm(g);
      DHB[gi] = av * g * s;
      float dgate = av * hb;
      DGB[gi] = dgate * s * (1.f + g*(1.f - s));
    EPI_END
  }
}

// ---- dw: C[j][d] = At[j][t].Bt[d][t], K=256; momentum + X + fro ----
__global__ __launch_bounds__(256) void k_dw(
    const u16* DGBTH, const u16* DGBTL, const u16* DHBTH, const u16* DHBTL,
    const u16* HIDTH, const u16* HIDTL,
    const u16* KTH, const u16* KTL, const u16* VTH, const u16* VTL,
    float* DM, float* X, const float* MI, float* fro, int c)
{
  __shared__ Smem sm;
  __shared__ float red[4];
  const int bx = blockIdx.x;
  const int nt = bx & 3, mt = (bx >> 2) & 3, bh = (bx >> 4) & 7, w = bx >> 7;
  const int m0 = mt*128, n0 = nt*128;
  const u16* Ah = (w==0 ? DGBTH : w==1 ? HIDTH : DHBTH) + (size_t)bh*131072;
  const u16* Al = (w==0 ? DGBTL : w==1 ? HIDTL : DHBTL) + (size_t)bh*131072;
  const u16* Bh = (w==1 ? VTH : KTH) + (size_t)bh*131072;
  const u16* Bl = (w==1 ? VTL : KTL) + (size_t)bh*131072;
  f32x16 acc[2][2] = {};
  mm_core<0>(Ah, Al, 256, m0, Bh, Bl, 256, n0, 256, sm, acc);
  TIDS;
  const float m_i = MI[bh*NUP + c];
  const int mat = bh*3 + w;
  float fs = 0.f;
  EPI_BEGIN
    size_t di = ((size_t)(w*8 + bh))*262144 + (size_t)gr*512 + gc;
    float dv = av + DM[di]*m_i;
    DM[di] = dv;
    X[(size_t)mat*262144 + (size_t)gr*512 + gc] = dv;
    fs += dv*dv;
  EPI_END
  #pragma unroll
  for (int off = 32; off > 0; off >>= 1) fs += __shfl_down(fs, off, 64);
  if ((tid & 63) == 0) red[tid >> 6] = fs;
  __syncthreads();
  if (tid == 0) atomicAdd(&fro[mat], red[0]+red[1]+red[2]+red[3]);
}

// ---- NS: Amat = NT(Xh, X) -> f16 h/l  (f16 2-product, B-side corrected) ----
__global__ __launch_bounds__(256) void k_nsA(
    const u16* XsH, const u16* XsL, u16* AoH, u16* AoL)
{
  __shared__ Smem sm;
  const int bx = blockIdx.x;
  const int nt = bx & 3, mt = (bx >> 2) & 3, mat = bx >> 4;
  const int m0 = mt*128, n0 = nt*128;
  const size_t mb = (size_t)mat*262144;
  f32x16 acc[2][2] = {};
  mm_core<1>(XsH + mb, nullptr, 512, m0, XsH + mb, XsL + mb, 512, n0, 512, sm, acc);
  TIDS;
  EPI_BEGIN
    size_t fi = mb + (size_t)gr*512 + gc;
    u16 hh, ll; split_h(av, hh, ll);
    AoH[fi] = hh; AoL[fi] = ll;
  EPI_END
}

// ---- NS: Bmat = cb*A + cc*NT(Ah, A) -> f16 h/l ----
__global__ __launch_bounds__(256) void k_nsB(
    const u16* AsH, const u16* AsL, u16* BoH, u16* BoL, float cb, float cc)
{
  __shared__ Smem sm;
  const int bx = blockIdx.x;
  const int nt = bx & 3, mt = (bx >> 2) & 3, mat = bx >> 4;
  const int m0 = mt*128, n0 = nt*128;
  const size_t mb = (size_t)mat*262144;
  f32x16 acc[2][2] = {};
  mm_core<1>(AsH + mb, nullptr, 512, m0, AsH + mb, AsL + mb, 512, n0, 512, sm, acc);
  TIDS;
  EPI_BEGIN
    size_t fi = mb + (size_t)gr*512 + gc;
    float af = h2f(AsH[fi]) + h2f(AsL[fi]);
    float bm = cb*af + cc*av;
    u16 hh, ll; split_h(bm, hh, ll);
    BoH[fi] = hh; BoL[fi] = ll;
  EPI_END
}

// ---- NS: X' = ca*X + Bmat @ Xh  (A-side corrected; B transpose-staged, h only) ----
struct SmemZ {
  u16 Ah[128][40]; u16 Al[128][40];
  unsigned B2h[128][20];
};

__global__ __launch_bounds__(256) void k_nsZ(
    const u16* BmH, const u16* BmL, const u16* XsH,
    float* X, u16* XnH, u16* XnL, float ca)
{
  __shared__ SmemZ sm;
  const int bx = blockIdx.x;
  const int nt = bx & 3, mt = (bx >> 2) & 3, mat = bx >> 4;
  const int m0 = mt*128, n0 = nt*128;
  const size_t mb = (size_t)mat*262144;
  TIDS;
  const int sr = tid >> 1, sc = (tid & 1) << 4;
  const int rp = tid & 15, cq = tid >> 4;
  const u16* pAh = BmH + mb + (size_t)(m0 + sr)*512 + sc;
  const u16* pAl = BmL + mb + (size_t)(m0 + sr)*512 + sc;
  const u16* pXh = XsH + mb + n0 + 8*cq;
  f32x16 acc[2][2] = {};
  int4 a0,a1,a2,a3,u0,u1;
  a0 = *(const int4*)(pAh); a1 = *(const int4*)(pAh+8);
  a2 = *(const int4*)(pAl); a3 = *(const int4*)(pAl+8);
  u0 = *(const int4*)(pXh + (size_t)(2*rp)*512);
  u1 = *(const int4*)(pXh + (size_t)(2*rp+1)*512);
  for (int kb = 0; kb < 512; kb += 32) {
    int4 na0,na1,na2,na3,nu0,nu1;
    const int kn = kb + 32;
    if (kn < 512) {
      na0 = *(const int4*)(pAh+kn); na1 = *(const int4*)(pAh+kn+8);
      na2 = *(const int4*)(pAl+kn); na3 = *(const int4*)(pAl+kn+8);
      nu0 = *(const int4*)(pXh + (size_t)(kn+2*rp)*512);
      nu1 = *(const int4*)(pXh + (size_t)(kn+2*rp+1)*512);
    }
    union { int4 v; u16 s[8]; } uh0, uh1;
    uh0.v = u0; uh1.v = u1;
    __syncthreads();
    *(int4*)&sm.Ah[sr][sc] = a0; *(int4*)&sm.Ah[sr][sc+8] = a1;
    *(int4*)&sm.Al[sr][sc] = a2; *(int4*)&sm.Al[sr][sc+8] = a3;
    #pragma unroll
    for (int e = 0; e < 8; ++e)
      sm.B2h[8*cq + e][rp] = (unsigned)uh0.s[e] | ((unsigned)uh1.s[e] << 16);
    __syncthreads();
    #pragma unroll
    for (int h = 0; h < 2; ++h) {
      v8h afh[2], afl[2], bfh[2];
      const int colA = h*16 + hv*8;
      const int colB = 8*h + 4*hv;
      #pragma unroll
      for (int i = 0; i < 2; ++i) {
        afh[i] = *(const v8h*)&sm.Ah[wm*64 + i*32 + l31][colA];
        afl[i] = *(const v8h*)&sm.Al[wm*64 + i*32 + l31][colA];
        bfh[i] = *(const v8h*)&sm.B2h[wn*64 + i*32 + l31][colB];
      }
      #pragma unroll
      for (int i = 0; i < 2; ++i)
        #pragma unroll
        for (int j = 0; j < 2; ++j) {
          acc[i][j] = __builtin_amdgcn_mfma_f32_32x32x16_f16(afh[i], bfh[j], acc[i][j], 0, 0, 0);
          acc[i][j] = __builtin_amdgcn_mfma_f32_32x32x16_f16(afl[i], bfh[j], acc[i][j], 0, 0, 0);
        }
    }
    if (kn < 512) { a0=na0; a1=na1; a2=na2; a3=na3; u0=nu0; u1=nu1; }
  }
  EPI_BEGIN
    size_t fi = mb + (size_t)gr*512 + gc;
    float nv = ca*X[fi] + av;
    X[fi] = nv;
    u16 hh, ll; split_h(nv, hh, ll);
    XnH[fi] = hh; XnL[fi] = ll;
  EPI_END
}

// ---- transpose+convert: fp32 src [R=256][C=512] (opt row scale) -> bf16 hi/lo [C][R] ----
__global__ __launch_bounds__(256) void k_tc(
    const float* DGB, const float* DHB, const float* HID,
    const float* kin, const float* vin,
    const float* lr0, const float* lr1, const float* lr2,
    u16* DGBTH, u16* DGBTL, u16* DHBTH, u16* DHBTL, u16* HIDTH, u16* HIDTL,
    u16* KTH, u16* KTL, u16* VTH, u16* VTL, int c)
{
  __shared__ u16 Th[64][72], Tl[64][72];
  const int bx = blockIdx.x;
  const int tile = bx & 31, bh = (bx >> 5) & 7, job = bx >> 8;
  const int rt = tile >> 3, ct = tile & 7;
  const int r0 = rt*64, c0 = ct*64;
  const float* src; const float* scale; u16* dH; u16* dL;
  size_t choff = (size_t)bh*2097152 + (size_t)c*131072;
  size_t aoff  = (size_t)bh*131072;
  if      (job == 0) { src = DGB + aoff; scale = lr0 + bh*SEQT + c*CS_; dH = DGBTH + aoff; dL = DGBTL + aoff; }
  else if (job == 1) { src = DHB + aoff; scale = lr2 + bh*SEQT + c*CS_; dH = DHBTH + aoff; dL = DHBTL + aoff; }
  else if (job == 2) { src = HID + aoff; scale = lr1 + bh*SEQT + c*CS_; dH = HIDTH + aoff; dL = HIDTL + aoff; }
  else if (job == 3) { src = kin + choff; scale = nullptr; dH = KTH + aoff; dL = KTL + aoff; }
  else               { src = vin + choff; scale = nullptr; dH = VTH + aoff; dL = VTL + aoff; }
  const int tid = threadIdx.x;
  const int rl = tid >> 4;
  const int cl = (tid & 15) << 2;
  #pragma unroll
  for (int it = 0; it < 4; ++it) {
    int row = rl + it*16;
    float sc = scale ? scale[r0 + row] : 1.0f;
    float4 v = *(const float4*)&src[(size_t)(r0 + row)*512 + c0 + cl];
    u16 h, l;
    split_bf(v.x*sc, h, l); Th[cl+0][row] = h; Tl[cl+0][row] = l;
    split_bf(v.y*sc, h, l); Th[cl+1][row] = h; Tl[cl+1][row] = l;
    split_bf(v.z*sc, h, l); Th[cl+2][row] = h; Tl[cl+2][row] = l;
    split_bf(v.w*sc, h, l); Th[cl+3][row] = h; Tl[cl+3][row] = l;
  }
  __syncthreads();
  const int c2 = tid >> 2;
  const int rg = (tid & 3) << 4;
  size_t dbase = (size_t)(c0 + c2)*256 + r0 + rg;
  *(int4*)&dH[dbase]     = *(int4*)&Th[c2][rg];
  *(int4*)&dH[dbase + 8] = *(int4*)&Th[c2][rg + 8];
  *(int4*)&dL[dbase]     = *(int4*)&Tl[c2][rg];
  *(int4*)&dL[dbase + 8] = *(int4*)&Tl[c2][rg + 8];
}

// ---- transpose bf16 hi/lo: W1T[j][d] <- WC w1 [d][j] ----
__global__ __launch_bounds__(256) void k_tb(
    const u16* WCH, const u16* WCL, u16* W1TH, u16* W1TL)
{
  __shared__ u16 Th[64][72], Tl[64][72];
  const int bx = blockIdx.x;
  const int ct = bx & 7, rt = (bx >> 3) & 7, bh = bx >> 6;
  const int r0 = rt*64, c0 = ct*64;
  const u16* sH = WCH + ((size_t)(8 + bh))*262144;
  const u16* sL = WCL + ((size_t)(8 + bh))*262144;
  const int tid = threadIdx.x;
  const int rl = tid >> 2;
  const int cg = (tid & 3) << 4;
  {
    union { int4 v[2]; u16 s[16]; } ah, al;
    ah.v[0] = *(const int4*)&sH[(size_t)(r0 + rl)*512 + c0 + cg];
    ah.v[1] = *(const int4*)&sH[(size_t)(r0 + rl)*512 + c0 + cg + 8];
    al.v[0] = *(const int4*)&sL[(size_t)(r0 + rl)*512 + c0 + cg];
    al.v[1] = *(const int4*)&sL[(size_t)(r0 + rl)*512 + c0 + cg + 8];
    #pragma unroll
    for (int e = 0; e < 16; ++e) { Th[cg + e][rl] = ah.s[e]; Tl[cg + e][rl] = al.s[e]; }
  }
  __syncthreads();
  const int c2 = tid >> 2;
  const int rg = (tid & 3) << 4;
  size_t dbase = (size_t)bh*262144 + (size_t)(c0 + c2)*512 + r0 + rg;
  *(int4*)&W1TH[dbase]     = *(int4*)&Th[c2][rg];
  *(int4*)&W1TH[dbase + 8] = *(int4*)&Th[c2][rg + 8];
  *(int4*)&W1TL[dbase]     = *(int4*)&Tl[c2][rg];
  *(int4*)&W1TL[dbase + 8] = *(int4*)&Tl[c2][rg + 8];
}

// ---- convert q,k,v chunk slices -> bf16 hi/lo ----
__global__ __launch_bounds__(256) void k_cvt_qkv(
    const float* q, const float* k, const float* v,
    u16* QcH, u16* QcL, u16* KcH, u16* KcL, u16* VcH, u16* VcL, int c)
{
  const int gid = blockIdx.x*256 + threadIdx.x;
  const size_t e8 = (size_t)gid * 8;
  const int arr = (int)(e8 / 1048576);
  const size_t r = e8 % 1048576;
  const int bh = (int)(r / 131072);
  const size_t off = r % 131072;
  const float* src = (arr==0 ? q : arr==1 ? k : v) + (size_t)bh*2097152 + (size_t)c*131072 + off;
  u16* dH = (arr==0 ? QcH : arr==1 ? KcH : VcH) + r;
  u16* dL = (arr==0 ? QcL : arr==1 ? KcL : VcL) + r;
  float4 v0 = *(const float4*)src;
  float4 v1 = *(const float4*)(src + 4);
  ushort4 h0, l0, h1, l1;
  split_bf(v0.x, h0.x, l0.x); split_bf(v0.y, h0.y, l0.y);
  split_bf(v0.z, h0.z, l0.z); split_bf(v0.w, h0.w, l0.w);
  split_bf(v1.x, h1.x, l1.x); split_bf(v1.y, h1.y, l1.y);
  split_bf(v1.z, h1.z, l1.z); split_bf(v1.w, h1.w, l1.w);
  *(ushort4*)(dH)     = h0; *(ushort4*)(dH + 4) = h1;
  *(ushort4*)(dL)     = l0; *(ushort4*)(dL + 4) = l1;
}

// ---- convert initial weights -> WCH/WCL (bf16 hi/lo) ----
__global__ __launch_bounds__(256) void k_cvt_w(
    const float* w0, const float* w1, const float* w2, u16* WCH, u16* WCL)
{
  const int gid = blockIdx.x*256 + threadIdx.x;
  const size_t e8 = (size_t)gid * 8;
  const int w = (int)(e8 / 2097152);
  const size_t off = e8 % 2097152;
  const float* src = (w==0 ? w0 : w==1 ? w1 : w2) + off;
  u16* dH = WCH + (size_t)w*2097152 + off;
  u16* dL = WCL + (size_t)w*2097152 + off;
  float4 v0 = *(const float4*)src;
  float4 v1 = *(const float4*)(src + 4);
  ushort4 h0, l0, h1, l1;
  split_bf(v0.x, h0.x, l0.x); split_bf(v0.y, h0.y, l0.y);
  split_bf(v0.z, h0.z, l0.z); split_bf(v0.w, h0.w, l0.w);
  split_bf(v1.x, h1.x, l1.x); split_bf(v1.y, h1.y, l1.y);
  split_bf(v1.z, h1.z, l1.z); split_bf(v1.w, h1.w, l1.w);
  *(ushort4*)(dH)     = h0; *(ushort4*)(dH + 4) = h1;
  *(ushort4*)(dL)     = l0; *(ushort4*)(dL + 4) = l1;
}

// ---- combine: job0 SQ=silu(P0q)*P2q -> bf16 hi/lo ; job1 HID=silu(GBA)*HBM fp32 ----
__global__ __launch_bounds__(256) void k_combine(
    const float* P0q, const float* P2q, const float* GBA, const float* HBMa,
    u16* SQH, u16* SQL, float* HID)
{
  const int bx = blockIdx.x;
  const int flag = bx >> 10;
  const int i4 = (bx & 1023)*256 + threadIdx.x;
  if (flag == 0) {
    float4 p0 = ((const float4*)P0q)[i4];
    float4 p2 = ((const float4*)P2q)[i4];
    float4 s;
    s.x = p0.x*sigm(p0.x)*p2.x; s.y = p0.y*sigm(p0.y)*p2.y;
    s.z = p0.z*sigm(p0.z)*p2.z; s.w = p0.w*sigm(p0.w)*p2.w;
    ushort4 h, l;
    split_bf(s.x, h.x, l.x); split_bf(s.y, h.y, l.y);
    split_bf(s.z, h.z, l.z); split_bf(s.w, h.w, l.w);
    ((ushort4*)SQH)[i4] = h; ((ushort4*)SQL)[i4] = l;
  } else {
    float4 g = ((const float4*)GBA)[i4];
    float4 hb = ((const float4*)HBMa)[i4];
    float4 o;
    o.x = g.x*sigm(g.x)*hb.x; o.y = g.y*sigm(g.y)*hb.y;
    o.z = g.z*sigm(g.z)*hb.z; o.w = g.w*sigm(g.w)*hb.w;
    ((float4*)HID)[i4] = o;
  }
}

// ---- X *= 1/(||X||_F+1e-7); write f16 hi/lo into step-0 slot ----
__global__ __launch_bounds__(256) void k_scale(
    float* X, u16* XH, u16* XL, const float* fro)
{
  const int gid = blockIdx.x*256 + threadIdx.x;
  const int mat = gid >> 16;
  float inv = 1.0f/(sqrtf(fro[mat]) + 1e-7f);
  float4 v = ((float4*)X)[gid];
  v.x *= inv; v.y *= inv; v.z *= inv; v.w *= inv;
  ((float4*)X)[gid] = v;
  ushort4 h, l;
  split_h(v.x, h.x, l.x); split_h(v.y, h.y, l.y);
  split_h(v.z, h.z, l.z); split_h(v.w, h.w, l.w);
  ((ushort4*)XH)[gid] = h; ((ushort4*)XL)[gid] = l;
}

// ---- weight update + rownorm rescale -> WM fp32, WC bf16 hi/lo ----
__global__ __launch_bounds__(256) void k_update2(
    const float* X, const float* XT1, float* wm, u16* WCH, u16* WCL,
    const float* wn, const float* mli, int c)
{
  const int gr = blockIdx.x*4 + (threadIdx.x >> 6);
  const int lane = threadIdx.x & 63;
  const int mat = gr >> 9, i = gr & 511;
  const int bh = mat / 3, w = mat - bh*3;
  const float* xrow = (w == 1) ? (XT1 + ((size_t)bh*512 + i)*512)
                               : (X   + (size_t)mat*262144 + (size_t)i*512);
  float* wmrow = wm + ((size_t)w*BH + bh)*262144 + (size_t)i*512;
  const float ml = mli[bh*NUP + c];
  float vreg[8];
  float ss = 0.f;
  #pragma unroll
  for (int u = 0; u < 8; ++u) {
    int col = lane + 64*u;
    float nv = wmrow[col] + xrow[col]*ml;
    vreg[u] = nv; ss += nv*nv;
    wmrow[col] = nv;
  }
  #pragma unroll
  for (int off = 32; off > 0; off >>= 1) ss += __shfl_xor(ss, off, 64);
  const float scale = wn[w*4096 + bh*512 + i] / (sqrtf(ss) + 1e-5f);
  size_t wb = ((size_t)w*BH + bh)*262144 + (size_t)i*512;
  #pragma unroll
  for (int u = 0; u < 8; ++u) {
    u16 h, l;
    split_bf(vreg[u]*scale, h, l);
    WCH[wb + lane + 64*u] = h;
    WCL[wb + lane + 64*u] = l;
  }
}

// ---- transpose final X1 (dw1 carried transposed) fp32 ----
__global__ __launch_bounds__(256) void transpose_x1(const float* __restrict__ X,
                                                    float* __restrict__ XT)
{
  __shared__ float tile[64][65];
  const int b = blockIdx.x;
  const int ct = b & 7, rt = (b >> 3) & 7, bh = b >> 6;
  const float* src = X + ((size_t)(bh*3 + 1))*262144;
  float* dst = XT + (size_t)bh*262144;
  const int r0 = rt*64, c0 = ct*64;
  const int lr = threadIdx.x >> 4, lc = (threadIdx.x & 15) << 2;
  #pragma unroll
  for (int i = 0; i < 4; ++i) {
    int row = lr + i*16;
    float4 vv = *(const float4*)&src[(size_t)(r0 + row)*512 + c0 + lc];
    tile[row][lc+0]=vv.x; tile[row][lc+1]=vv.y; tile[row][lc+2]=vv.z; tile[row][lc+3]=vv.w;
  }
  __syncthreads();
  #pragma unroll
  for (int i = 0; i < 4; ++i) {
    int row = lr + i*16;
    float4 vv = make_float4(tile[lc+0][row], tile[lc+1][row], tile[lc+2][row], tile[lc+3][row]);
    *(float4*)&dst[(size_t)(c0 + row)*512 + r0 + lc] = vv;
  }
}

// ---- initial per-row norms of w0/w1/w2 ----
__global__ __launch_bounds__(256) void wnorm_kernel(
    const float* __restrict__ w0, const float* __restrict__ w1,
    const float* __restrict__ w2, float* __restrict__ wn)
{
  const int gr = blockIdx.x*4 + (threadIdx.x >> 6);
  const int lane = threadIdx.x & 63;
  const int w = gr >> 12, bh = (gr >> 9) & 7, i = gr & 511;
  const float* src = (w==0 ? w0 : (w==1 ? w1 : w2)) + ((size_t)bh*512 + i)*512;
  float ss = 0.f;
  #pragma unroll
  for (int u = 0; u < 8; ++u) { float x = src[lane + 64*u]; ss += x*x; }
  #pragma unroll
  for (int off = 32; off > 0; off >>= 1) ss += __shfl_xor(ss, off, 64);
  if (lane == 0) wn[gr] = sqrtf(ss);
}

// ---- per-(bh,chunk) scalars ----
__global__ __launch_bounds__(64) void scalars_kernel(
    const float* __restrict__ mom, const float* __restrict__ mlr,
    float* __restrict__ mi, float* __restrict__ mli)
{
  const int b = blockIdx.x;
  const int bh = b / NUP, c = b % NUP;
  const int lane = threadIdx.x;
  const float* mp = mom + (size_t)bh*SEQT + (size_t)c*CS_;
  const float* lp = mlr + (size_t)bh*SEQT + (size_t)c*CS_;
  float s1 = 0.f, s2 = 0.f;
  #pragma unroll
  for (int u = 0; u < 4; ++u) { s1 += mp[lane + 64*u]; s2 += lp[lane + 64*u]; }
  #pragma unroll
  for (int off = 32; off > 0; off >>= 1) {
    s1 += __shfl_xor(s1, off, 64);
    s2 += __shfl_xor(s2, off, 64);
  }
  if (lane == 0) { mi[bh*NUP + c] = s1/256.f; mli[bh*NUP + c] = s2/256.f; }
}

static const float NSC[5][3] = {
  {4.0848f, -6.8946f, 2.9270f},
  {3.9505f, -6.3029f, 2.6377f},
  {3.7418f, -5.5913f, 2.3037f},
  {2.8769f, -3.1427f, 1.2046f},
  {2.8366f, -3.0525f, 1.2012f}};

// ============================ FALLBACK (fp32) PATH ===========================
#define SZ_W    (3ull*BH*DI_*DD)
#define SZ_W1   ((size_t)BH*DI_*DD)
#define SZ_ACT  ((size_t)BH*DI_*CS_)
#define OFF_WM  0ull
#define OFF_WC  (OFF_WM + SZ_W)
#define OFF_DM  (OFF_WC + SZ_W)
#define OFF_X   (OFF_DM + SZ_W)
#define OFF_A   (OFF_X  + SZ_W)
#define OFF_SQ  (OFF_A  + SZ_W)
#define OFF_GBA (OFF_SQ  + SZ_ACT)
#define OFF_HBM (OFF_GBA + SZ_ACT)
#define OFF_HID (OFF_HBM + SZ_ACT)
#define OFF_DGB (OFF_HID + SZ_ACT)
#define OFF_DHB (OFF_DGB + SZ_ACT)
#define OFF_Y   OFF_SQ
#define OFF_FRO (OFF_DHB + SZ_ACT)
#define OFF_MI  (OFF_FRO + 360)
#define OFF_MLI (OFF_MI  + 120)
#define OFF_WN  (OFF_MLI + 120)

#define FMA44(ACC,AV,BV) do{ \
  ACC[0][0]+=AV.x*BV.x; ACC[0][1]+=AV.x*BV.y; ACC[0][2]+=AV.x*BV.z; ACC[0][3]+=AV.x*BV.w; \
  ACC[1][0]+=AV.y*BV.x; ACC[1][1]+=AV.y*BV.y; ACC[1][2]+=AV.y*BV.z; ACC[1][3]+=AV.y*BV.w; \
  ACC[2][0]+=AV.z*BV.x; ACC[2][1]+=AV.z*BV.y; ACC[2][2]+=AV.z*BV.z; ACC[2][3]+=AV.z*BV.w; \
  ACC[3][0]+=AV.w*BV.x; ACC[3][1]+=AV.w*BV.y; ACC[3][2]+=AV.w*BV.z; ACC[3][3]+=AV.w*BV.w; \
}while(0)

__device__ __forceinline__ void gemm_nn_tile(
    const float* __restrict__ A, int lda,
    const float* __restrict__ B, int ldb,
    const float* __restrict__ lsc,
    int K, int m0, int n0, float acc[4][4],
    float (&As)[16][68], float (&Bs)[16][68])
{
  const int tid = threadIdx.x;
  const int ar = tid >> 2, ac = (tid & 3) << 2;
  const int br = tid >> 4, bc = (tid & 15) << 2;
  const int my = tid & 15, nx = tid >> 4;
  for (int k0 = 0; k0 < K; k0 += 16) {
    float4 av = *(const float4*)&A[(size_t)(m0 + ar) * lda + k0 + ac];
    float4 bv = *(const float4*)&B[(size_t)(k0 + br) * ldb + n0 + bc];
    if (lsc) { float s = lsc[k0 + br]; bv.x*=s; bv.y*=s; bv.z*=s; bv.w*=s; }
    __syncthreads();
    As[ac+0][ar]=av.x; As[ac+1][ar]=av.y; As[ac+2][ar]=av.z; As[ac+3][ar]=av.w;
    *(float4*)&Bs[br][bc] = bv;
    __syncthreads();
    #pragma unroll
    for (int kk = 0; kk < 16; ++kk) {
      float4 a = *(const float4*)&As[kk][my*4];
      float4 b = *(const float4*)&Bs[kk][nx*4];
      FMA44(acc,a,b);
    }
  }
}

__global__ __launch_bounds__(256) void fwd_kernel(
    const float* __restrict__ w0c, const float* __restrict__ w2c,
    const float* __restrict__ q, const float* __restrict__ kin,
    float* __restrict__ sq, float* __restrict__ gba,
    float* __restrict__ hbmp, float* __restrict__ hid,
    int c, int nsrc)
{
  __shared__ float As0[16][68], As1[16][68], Bs[16][68];
  const int b = blockIdx.x;
  const int nt = b & 3, mt = (b >> 2) & 7;
  const int src = (b >> 5) % nsrc;
  const int bh = b / (32 * nsrc);
  const int m0 = mt * 64, n0 = nt * 64;
  const float* A0 = w0c + (size_t)bh * DI_ * DD;
  const float* A1 = w2c + (size_t)bh * DI_ * DD;
  const float* S  = (src == 0 ? q : kin) + ((size_t)bh * SEQT + (size_t)c * CS_) * DD;
  float acc0[4][4] = {}, acc1[4][4] = {};
  const int tid = threadIdx.x;
  const int r = tid >> 2, c4 = (tid & 3) << 2;
  const int my = tid & 15, nx = tid >> 4;
  for (int k0 = 0; k0 < DD; k0 += 16) {
    float4 a0 = *(const float4*)&A0[(size_t)(m0 + r) * DD + k0 + c4];
    float4 a1 = *(const float4*)&A1[(size_t)(m0 + r) * DD + k0 + c4];
    float4 bv = *(const float4*)&S [(size_t)(n0 + r) * DD + k0 + c4];
    __syncthreads();
    As0[c4+0][r]=a0.x; As0[c4+1][r]=a0.y; As0[c4+2][r]=a0.z; As0[c4+3][r]=a0.w;
    As1[c4+0][r]=a1.x; As1[c4+1][r]=a1.y; As1[c4+2][r]=a1.z; As1[c4+3][r]=a1.w;
    Bs [c4+0][r]=bv.x; Bs [c4+1][r]=bv.y; Bs [c4+2][r]=bv.z; Bs [c4+3][r]=bv.w;
    __syncthreads();
    #pragma unroll
    for (int kk = 0; kk < 16; ++kk) {
      float4 a  = *(const float4*)&As0[kk][my*4];
      float4 a2 = *(const float4*)&As1[kk][my*4];
      float4 bb = *(const float4*)&Bs [kk][nx*4];
      FMA44(acc0,a,bb);
      FMA44(acc1,a2,bb);
    }
  }
  #pragma unroll
  for (int um = 0; um < 4; ++um) {
    int j = m0 + my*4 + um;
    size_t base = ((size_t)bh * DI_ + j) * CS_ + n0 + nx*4;
    if (src == 0) {
      float4 o;
      o.x = acc0[um][0]*sigm(acc0[um][0])*acc1[um][0];
      o.y = acc0[um][1]*sigm(acc0[um][1])*acc1[um][1];
      o.z = acc0[um][2]*sigm(acc0[um][2])*acc1[um][2];
      o.w = acc0[um][3]*sigm(acc0[um][3])*acc1[um][3];
      *(float4*)&sq[base] = o;
    } else {
      float4 g = make_float4(acc0[um][0],acc0[um][1],acc0[um][2],acc0[um][3]);
      float4 h = make_float4(acc1[um][0],acc1[um][1],acc1[um][2],acc1[um][3]);
      float4 hd;
      hd.x = g.x*sigm(g.x)*h.x; hd.y = g.y*sigm(g.y)*h.y;
      hd.z = g.z*sigm(g.z)*h.z; hd.w = g.w*sigm(g.w)*h.w;
      *(float4*)&gba[base]  = g;
      *(float4*)&hbmp[base] = h;
      *(float4*)&hid[base]  = hd;
    }
  }
}

__global__ __launch_bounds__(256) void out_kernel(
    const float* __restrict__ w1c, const float* __restrict__ sq,
    float* __restrict__ out, int c)
{
  __shared__ float As[16][68], Bs[16][68];
  const int b = blockIdx.x;
  const int nt = b & 3, mt = (b >> 2) & 7, bh = b >> 5;
  const int m0 = mt * 64, n0 = nt * 64;
  float acc[4][4] = {};
  gemm_nn_tile(w1c + (size_t)bh*DD*DI_, DI_, sq + (size_t)bh*DI_*CS_, CS_,
               nullptr, DI_, m0, n0, acc, As, Bs);
  const int my = threadIdx.x & 15, nx = threadIdx.x >> 4;
  #pragma unroll
  for (int un = 0; un < 4; ++un) {
    int t = n0 + nx*4 + un;
    float4 o = make_float4(acc[0][un],acc[1][un],acc[2][un],acc[3][un]);
    *(float4*)&out[((size_t)bh*SEQT + (size_t)c*CS_ + t)*DD + m0 + my*4] = o;
  }
}

__global__ __launch_bounds__(256) void dh_kernel(
    const float* __restrict__ vin, const float* __restrict__ w1c,
    const float* __restrict__ gba, const float* __restrict__ hbmp,
    float* __restrict__ dgb, float* __restrict__ dhb, int c)
{
  __shared__ float As[16][68], Bs[16][68];
  const int b = blockIdx.x;
  const int nt = b & 7, mt = (b >> 3) & 3, bh = b >> 5;
  const int m0 = mt * 64, n0 = nt * 64;
  float acc[4][4] = {};
  gemm_nn_tile(vin + ((size_t)bh*SEQT + (size_t)c*CS_)*DD, DD,
               w1c + (size_t)bh*DD*DI_, DI_, nullptr, DD, m0, n0, acc, As, Bs);
  const int my = threadIdx.x & 15, nx = threadIdx.x >> 4;
  #pragma unroll
  for (int un = 0; un < 4; ++un) {
    int j = n0 + nx*4 + un;
    size_t idx = ((size_t)bh*DI_ + j)*CS_ + m0 + my*4;
    float4 g4 = *(const float4*)&gba[idx];
    float4 h4 = *(const float4*)&hbmp[idx];
    float ge[4] = {g4.x,g4.y,g4.z,g4.w};
    float hb[4] = {h4.x,h4.y,h4.z,h4.w};
    float dg[4], dh[4];
    #pragma unroll
    for (int u = 0; u < 4; ++u) {
      float e = acc[u][un];
      float s = sigm(ge[u]);
      dh[u] = e * ge[u] * s;
      float dgate = e * hb[u];
      dg[u] = dgate * s * (1.f + ge[u]*(1.f - s));
    }
    *(float4*)&dgb[idx] = make_float4(dg[0],dg[1],dg[2],dg[3]);
    *(float4*)&dhb[idx] = make_float4(dh[0],dh[1],dh[2],dh[3]);
  }
}

__global__ __launch_bounds__(256) void dw_kernel(
    const float* __restrict__ dgb, const float* __restrict__ dhb,
    const float* __restrict__ hid, const float* __restrict__ kin,
    const float* __restrict__ vin,
    const float* __restrict__ lr0, const float* __restrict__ lr1,
    const float* __restrict__ lr2,
    float* __restrict__ dm, float* __restrict__ X,
    const float* __restrict__ mi, float* __restrict__ fro, int c)
{
  __shared__ float As[16][68], Bs[16][68];
  __shared__ float red[4];
  const int b = blockIdx.x;
  const int nt = b & 7, mt = (b >> 3) & 7, bh = (b >> 6) & 7, w = b >> 9;
  const int m0 = mt * 64, n0 = nt * 64;
  const float* Aop = (w==0 ? dgb : (w==1 ? hid : dhb)) + (size_t)bh*DI_*CS_;
  const float* Bop = (w==1 ? vin : kin) + ((size_t)bh*SEQT + (size_t)c*CS_)*DD;
  const float* l   = (w==0 ? lr0 : (w==1 ? lr1 : lr2)) + (size_t)bh*SEQT + (size_t)c*CS_;
  float acc[4][4] = {};
  gemm_nn_tile(Aop, CS_, Bop, DD, l, CS_, m0, n0, acc, As, Bs);
  const int my = threadIdx.x & 15, nx = threadIdx.x >> 4;
  const float m_i = mi[bh*NUP + c];
  const int mat = bh*3 + w;
  const size_t base = (size_t)mat * DI_ * DD;
  float fs = 0.f;
  #pragma unroll
  for (int um = 0; um < 4; ++um) {
    size_t idx = base + (size_t)(m0 + my*4 + um)*DD + n0 + nx*4;
    float4 dmv = *(const float4*)&dm[idx];
    float4 dv;
    dv.x = acc[um][0] + dmv.x*m_i; dv.y = acc[um][1] + dmv.y*m_i;
    dv.z = acc[um][2] + dmv.z*m_i; dv.w = acc[um][3] + dmv.w*m_i;
    *(float4*)&dm[idx] = dv;
    *(float4*)&X[idx]  = dv;
    fs += dv.x*dv.x + dv.y*dv.y + dv.z*dv.z + dv.w*dv.w;
  }
  #pragma unroll
  for (int off = 32; off > 0; off >>= 1) fs += __shfl_down(fs, off, 64);
  const int wid = threadIdx.x >> 6;
  if ((threadIdx.x & 63) == 0) red[wid] = fs;
  __syncthreads();
  if (threadIdx.x == 0) atomicAdd(&fro[mat], red[0]+red[1]+red[2]+red[3]);
}

__global__ __launch_bounds__(256) void ns_scale_kernel(float* __restrict__ X,
                                                       const float* __restrict__ fro)
{
  int gid = blockIdx.x*256 + threadIdx.x;
  int mat = gid >> 16;
  float inv = 1.0f/(sqrtf(fro[mat]) + 1e-7f);
  float4* p = ((float4*)X) + gid;
  float4 v = *p; v.x*=inv; v.y*=inv; v.z*=inv; v.w*=inv; *p = v;
}

__global__ __launch_bounds__(256) void nsA_kernel(const float* __restrict__ X,
                                                  float* __restrict__ Ab)
{
  __shared__ float As[16][68], Bs[16][68];
  const int b = blockIdx.x;
  const int nt = b & 7, mt = (b >> 3) & 7, mat = b >> 6;
  const int m0 = mt*64, n0 = nt*64;
  const float* Xm = X + (size_t)mat * DI_ * DD;
  float acc[4][4] = {};
  const int tid = threadIdx.x;
  const int r = tid >> 2, c4 = (tid & 3) << 2;
  const int my = tid & 15, nx = tid >> 4;
  for (int k0 = 0; k0 < DD; k0 += 16) {
    float4 av = *(const float4*)&Xm[(size_t)(m0 + r)*DD + k0 + c4];
    float4 bv = *(const float4*)&Xm[(size_t)(n0 + r)*DD + k0 + c4];
    __syncthreads();
    As[c4+0][r]=av.x; As[c4+1][r]=av.y; As[c4+2][r]=av.z; As[c4+3][r]=av.w;
    Bs[c4+0][r]=bv.x; Bs[c4+1][r]=bv.y; Bs[c4+2][r]=bv.z; Bs[c4+3][r]=bv.w;
    __syncthreads();
    #pragma unroll
    for (int kk = 0; kk < 16; ++kk) {
      float4 a = *(const float4*)&As[kk][my*4];
      float4 bb = *(const float4*)&Bs[kk][nx*4];
      FMA44(acc,a,bb);
    }
  }
  #pragma unroll
  for (int um = 0; um < 4; ++um) {
    size_t idx = (size_t)mat*DI_*DD + (size_t)(m0 + my*4 + um)*DD + n0 + nx*4;
    *(float4*)&Ab[idx] = make_float4(acc[um][0],acc[um][1],acc[um][2],acc[um][3]);
  }
}

__global__ __launch_bounds__(256) void nsY_kernel(const float* __restrict__ Ab,
                                                  const float* __restrict__ X,
                                                  float* __restrict__ Y)
{
  __shared__ float As[16][68], Bs[16][68];
  const int b = blockIdx.x;
  const int nt = b & 7, mt = (b >> 3) & 7, mat = b >> 6;
  const int m0 = mt*64, n0 = nt*64;
  float acc[4][4] = {};
  gemm_nn_tile(Ab + (size_t)mat*DI_*DD, DD, X + (size_t)mat*DI_*DD, DD,
               nullptr, DD, m0, n0, acc, As, Bs);
  const int my = threadIdx.x & 15, nx = threadIdx.x >> 4;
  #pragma unroll
  for (int um = 0; um < 4; ++um) {
    size_t idx = (size_t)mat*DI_*DD + (size_t)(m0 + my*4 + um)*DD + n0 + nx*4;
    *(float4*)&Y[idx] = make_float4(acc[um][0],acc[um][1],acc[um][2],acc[um][3]);
  }
}

__global__ __launch_bounds__(256) void nsZ_kernel(const float* __restrict__ Ab,
                                                  const float* __restrict__ Y,
                                                  float* __restrict__ X,
                                                  float ca, float cb, float cg)
{
  __shared__ float As[16][68], Bs[16][68];
  const int b = blockIdx.x;
  const int nt = b & 7, mt = (b >> 3) & 7, mat = b >> 6;
  const int m0 = mt*64, n0 = nt*64;
  float acc[4][4] = {};
  gemm_nn_tile(Ab + (size_t)mat*DI_*DD, DD, Y + (size_t)mat*DI_*DD, DD,
               nullptr, DD, m0, n0, acc, As, Bs);
  const int my = threadIdx.x & 15, nx = threadIdx.x >> 4;
  #pragma unroll
  for (int um = 0; um < 4; ++um) {
    size_t idx = (size_t)mat*DI_*DD + (size_t)(m0 + my*4 + um)*DD + n0 + nx*4;
    float4 xv = *(const float4*)&X[idx];
    float4 yv = *(const float4*)&Y[idx];
    float4 ov;
    ov.x = ca*xv.x + cb*yv.x + cg*acc[um][0];
    ov.y = ca*xv.y + cb*yv.y + cg*acc[um][1];
    ov.z = ca*xv.z + cb*yv.z + cg*acc[um][2];
    ov.w = ca*xv.w + cb*yv.w + cg*acc[um][3];
    *(float4*)&X[idx] = ov;
  }
}

__global__ __launch_bounds__(256) void update_kernel(
    const float* __restrict__ X, const float* __restrict__ XT,
    float* __restrict__ wm, float* __restrict__ wc,
    const float* __restrict__ wn, const float* __restrict__ mli, int c)
{
  const int gr = blockIdx.x*4 + (threadIdx.x >> 6);
  const int lane = threadIdx.x & 63;
  const int mat = gr >> 9, i = gr & 511;
  const int bh = mat / 3, w = mat - bh*3;
  const float* xrow = (w == 1) ? (XT + ((size_t)bh*512 + i)*512)
                               : (X  + (size_t)mat*DI_*DD + (size_t)i*512);
  float* wmrow = wm + ((size_t)w*BH + bh)*DI_*DD + (size_t)i*512;
  float* wcrow = wc + ((size_t)w*BH + bh)*DI_*DD + (size_t)i*512;
  const float ml = mli[bh*NUP + c];
  float vreg[8];
  float ss = 0.f;
  #pragma unroll
  for (int u = 0; u < 8; ++u) {
    int col = lane + 64*u;
    float nv = wmrow[col] + xrow[col]*ml;
    vreg[u] = nv; ss += nv*nv;
    wmrow[col] = nv;
  }
  #pragma unroll
  for (int off = 32; off > 0; off >>= 1) ss += __shfl_xor(ss, off, 64);
  const float scale = wn[w*4096 + bh*512 + i] / (sqrtf(ss) + 1e-5f);
  #pragma unroll
  for (int u = 0; u < 8; ++u) wcrow[lane + 64*u] = vreg[u]*scale;
}

// ================================ LAUNCHERS =================================

static void launch_fallback(void* const* d_in, void* d_out, void* d_ws, hipStream_t stream)
{
  const float* w0  = (const float*)d_in[0];
  const float* w1  = (const float*)d_in[1];
  const float* w2  = (const float*)d_in[2];
  const float* q   = (const float*)d_in[3];
  const float* k   = (const float*)d_in[4];
  const float* v   = (const float*)d_in[5];
  const float* lr0 = (const float*)d_in[6];
  const float* lr1 = (const float*)d_in[7];
  const float* lr2 = (const float*)d_in[8];
  const float* mom = (const float*)d_in[9];
  const float* mlr = (const float*)d_in[10];
  float* out = (float*)d_out;
  float* ws  = (float*)d_ws;

  float* WM  = ws + OFF_WM;  float* WC  = ws + OFF_WC;  float* DM  = ws + OFF_DM;
  float* X   = ws + OFF_X;   float* A   = ws + OFF_A;   float* SQ  = ws + OFF_SQ;
  float* GBA = ws + OFF_GBA; float* HBMb= ws + OFF_HBM; float* HID = ws + OFF_HID;
  float* DGB = ws + OFF_DGB; float* DHB = ws + OFF_DHB; float* Y   = ws + OFF_Y;
  float* FRO = ws + OFF_FRO; float* MI  = ws + OFF_MI;  float* MLI = ws + OFF_MLI;
  float* WN  = ws + OFF_WN;

  for (int w = 0; w < 3; ++w) {
    const float* src = (w==0 ? w0 : (w==1 ? w1 : w2));
    hipMemcpyAsync(WM + (size_t)w*SZ_W1, src, SZ_W1*sizeof(float),
                   hipMemcpyDeviceToDevice, stream);
    hipMemcpyAsync(WC + (size_t)w*SZ_W1, src, SZ_W1*sizeof(float),
                   hipMemcpyDeviceToDevice, stream);
  }
  hipMemsetAsync(DM, 0, SZ_W*sizeof(float), stream);
  hipMemsetAsync(FRO, 0, 360*sizeof(float), stream);
  wnorm_kernel<<<3072, 256, 0, stream>>>(w0, w1, w2, WN);
  scalars_kernel<<<BH*NUP, 64, 0, stream>>>(mom, mlr, MI, MLI);

  for (int c = 0; c < NUP; ++c) {
    fwd_kernel<<<512, 256, 0, stream>>>(WC, WC + 2*SZ_W1, q, k, SQ, GBA, HBMb, HID, c, 2);
    out_kernel<<<256, 256, 0, stream>>>(WC + SZ_W1, SQ, out, c);
    dh_kernel<<<256, 256, 0, stream>>>(v, WC + SZ_W1, GBA, HBMb, DGB, DHB, c);
    dw_kernel<<<1536, 256, 0, stream>>>(DGB, DHB, HID, k, v, lr0, lr1, lr2,
                                        DM, X, MI, FRO + c*24, c);
    ns_scale_kernel<<<6144, 256, 0, stream>>>(X, FRO + c*24);
    for (int s = 0; s < 5; ++s) {
      nsA_kernel<<<1536, 256, 0, stream>>>(X, A);
      nsY_kernel<<<1536, 256, 0, stream>>>(A, X, Y);
      nsZ_kernel<<<1536, 256, 0, stream>>>(A, Y, X, NSC[s][0], NSC[s][1], NSC[s][2]);
    }
    transpose_x1<<<512, 256, 0, stream>>>(X, Y);
    update_kernel<<<3072, 256, 0, stream>>>(X, Y, WM, WC, WN, MLI, c);
  }
  fwd_kernel<<<256, 256, 0, stream>>>(WC, WC + 2*SZ_W1, q, k, SQ, GBA, HBMb, HID, NUP, 1);
  out_kernel<<<256, 256, 0, stream>>>(WC + SZ_W1, SQ, out, NUP);
}

static void launch_primary(void* const* d_in, void* d_out, void* d_ws, hipStream_t stream)
{
  const float* w0  = (const float*)d_in[0];
  const float* w1  = (const float*)d_in[1];
  const float* w2  = (const float*)d_in[2];
  const float* q   = (const float*)d_in[3];
  const float* kk  = (const float*)d_in[4];
  const float* v   = (const float*)d_in[5];
  const float* lr0 = (const float*)d_in[6];
  const float* lr1 = (const float*)d_in[7];
  const float* lr2 = (const float*)d_in[8];
  const float* mom = (const float*)d_in[9];
  const float* mlr = (const float*)d_in[10];
  float* out = (float*)d_out;
  char* base = (char*)d_ws;

  float* WM   = (float*)(base + 0);
  float* DM   = (float*)(base + 25165824);
  float* Xf   = (float*)(base + 50331648);
  u16* WCH    = (u16*)(base + 75497472);
  u16* WCL    = (u16*)(base + 88080384);
  char* OVER  = base + 100663296;
  float* FRO  = (float*)(base + 176160768);
  float* MI   = (float*)(base + 176162208);
  float* MLI  = (float*)(base + 176162688);
  float* WN   = (float*)(base + 176163168);

  u16* S1H = (u16*)(OVER);             u16* S1L = (u16*)(OVER + 12582912);
  u16* S2H = (u16*)(OVER + 25165824);  u16* S2L = (u16*)(OVER + 37748736);
  u16* S3H = (u16*)(OVER + 50331648);  u16* S3L = (u16*)(OVER + 62914560);

  float* P0q  = (float*)(OVER + 0);
  float* P2q  = (float*)(OVER + 4194304);
  float* GBA  = (float*)(OVER + 8388608);
  float* HBMa = (float*)(OVER + 12582912);
  float* HID  = (float*)(OVER + 16777216);
  float* DGB  = (float*)(OVER + 20971520);
  float* DHB  = (float*)(OVER + 25165824);
  u16* QcH = (u16*)(OVER + 29360128);  u16* QcL = (u16*)(OVER + 31457280);
  u16* KcH = (u16*)(OVER + 33554432);  u16* KcL = (u16*)(OVER + 35651584);
  u16* VcH = (u16*)(OVER + 37748736);  u16* VcL = (u16*)(OVER + 39845888);
  u16* KTH = (u16*)(OVER + 41943040);  u16* KTL = (u16*)(OVER + 44040192);
  u16* VTH = (u16*)(OVER + 46137344);  u16* VTL = (u16*)(OVER + 48234496);
  u16* SQH = (u16*)(OVER + 50331648);  u16* SQL = (u16*)(OVER + 52428800);
  u16* DGBTH = (u16*)(OVER + 54525952); u16* DGBTL = (u16*)(OVER + 56623104);
  u16* DHBTH = (u16*)(OVER + 58720256); u16* DHBTL = (u16*)(OVER + 60817408);
  u16* HIDTH = (u16*)(OVER + 62914560); u16* HIDTL = (u16*)(OVER + 65011712);
  u16* W1TH = (u16*)(OVER + 67108864); u16* W1TL = (u16*)(OVER + 71303168);
  float* XT1 = (float*)(OVER + 50331648);  // update-time scratch (S3 region)

  for (int w = 0; w < 3; ++w) {
    const float* src = (w==0 ? w0 : (w==1 ? w1 : w2));
    hipMemcpyAsync(WM + (size_t)w*2097152, src, 2097152*sizeof(float),
                   hipMemcpyDeviceToDevice, stream);
  }
  hipMemsetAsync(DM, 0, 25165824, stream);
  hipMemsetAsync(FRO, 0, 360*sizeof(float), stream);
  k_cvt_w<<<3072, 256, 0, stream>>>(w0, w1, w2, WCH, WCL);
  wnorm_kernel<<<3072, 256, 0, stream>>>(w0, w1, w2, WN);
  scalars_kernel<<<BH*NUP, 64, 0, stream>>>(mom, mlr, MI, MLI);

  for (int c = 0; c < NUP; ++c) {
    k_cvt_qkv<<<1536, 256, 0, stream>>>(q, kk, v, QcH, QcL, KcH, KcL, VcH, VcL, c);
    k_tb<<<512, 256, 0, stream>>>(WCH, WCL, W1TH, W1TL);
    k_fwd<<<256, 256, 0, stream>>>(QcH, QcL, KcH, KcL, WCH, WCL, P0q, P2q, GBA, HBMa);
    k_combine<<<2048, 256, 0, stream>>>(P0q, P2q, GBA, HBMa, SQH, SQL, HID);
    k_outdh<<<128, 256, 0, stream>>>(SQH, SQL, WCH, WCL, VcH, VcL, W1TH, W1TL,
                                     GBA, HBMa, DGB, DHB, out, c);
    k_tc<<<1280, 256, 0, stream>>>(DGB, DHB, HID, kk, v, lr0, lr1, lr2,
                                   DGBTH, DGBTL, DHBTH, DHBTL, HIDTH, HIDTL,
                                   KTH, KTL, VTH, VTL, c);
    k_dw<<<384, 256, 0, stream>>>(DGBTH, DGBTL, DHBTH, DHBTL, HIDTH, HIDTL,
                                  KTH, KTL, VTH, VTL, DM, Xf, MI, FRO + c*24, c);
    k_scale<<<6144, 256, 0, stream>>>(Xf, S1H, S1L, FRO + c*24);
    for (int s = 0; s < 5; ++s) {
      u16* xsH = (s & 1) ? S2H : S1H;  u16* xsL = (s & 1) ? S2L : S1L;
      u16* asH = (s & 1) ? S1H : S2H;  u16* asL = (s & 1) ? S1L : S2L;
      k_nsA<<<384, 256, 0, stream>>>(xsH, xsL, asH, asL);
      k_nsB<<<384, 256, 0, stream>>>(asH, asL, S3H, S3L, NSC[s][1], NSC[s][2]);
      k_nsZ<<<384, 256, 0, stream>>>(S3H, S3L, xsH, Xf, asH, asL, NSC[s][0]);
    }
    transpose_x1<<<512, 256, 0, stream>>>(Xf, XT1);
    k_update2<<<3072, 256, 0, stream>>>(Xf, XT1, WM, WCH, WCL, WN, MLI, c);
  }
  // final forward-only chunk
  k_cvt_qkv<<<1536, 256, 0, stream>>>(q, kk, v, QcH, QcL, KcH, KcL, VcH, VcL, NUP);
  k_fwd<<<128, 256, 0, stream>>>(QcH, QcL, KcH, KcL, WCH, WCL, P0q, P2q, GBA, HBMa);
  k_combine<<<1024, 256, 0, stream>>>(P0q, P2q, GBA, HBMa, SQH, SQL, HID);
  k_outdh<<<64, 256, 0, stream>>>(SQH, SQL, WCH, WCL, VcH, VcL, W1TH, W1TL,
                                  GBA, HBMa, DGB, DHB, out, NUP);
}

extern "C" void kernel_launch(void* const* d_in, const int* in_sizes, int n_in,
                              void* d_out, int out_size, void* d_ws, size_t ws_size,
                              hipStream_t stream)
{
  (void)in_sizes; (void)n_in; (void)out_size;
  if (ws_size >= 176212320ull) {
    launch_primary(d_in, d_out, d_ws, stream);
  } else {
    launch_fallback(d_in, d_out, d_ws, stream);
  }
}